// Round 8
// baseline (803.147 us; speedup 1.0000x reference)
//
#include <hip/hip_runtime.h>
#include <stdint.h>

#define NN 100000
#define NE 1600000
#define DIM 128
#define BN_EPS 1e-5f
#define NBUCK 391               // ceil(NN/256) node blocks for the offs scan
#define NBLK_GEMM 1563          // ceil(100000/64)
#define NBLK_AGG 6250           // 16 nodes/block: 4 waves x 4 nodes
#define NB_HIST 1024            // grid for grid-strided edge kernels
#define CSR_PAD 32              // zero-norm pad records past NE (2-deep prefetch)
#define NREP 64                 // stats replica slots (contention: 6250/64 ~= 98 per addr)

typedef unsigned int uint;
typedef unsigned short ushort;
typedef unsigned char uchar;
typedef __attribute__((ext_vector_type(8))) short short8;   // 8 x bf16 (4 VGPRs)
typedef __attribute__((ext_vector_type(4))) float f32x4;
typedef __attribute__((ext_vector_type(2))) float v2f;      // packed fp32 pair

// ---------------- bf16 helpers ----------------

static __device__ __forceinline__ ushort f2bf(float f) {
    uint u = __float_as_uint(f);
    u += 0x7FFF + ((u >> 16) & 1);   // round-to-nearest-even
    return (ushort)(u >> 16);
}
static __device__ __forceinline__ float bf_lo(uint p) { return __uint_as_float(p << 16); }
static __device__ __forceinline__ float bf_hi(uint p) { return __uint_as_float(p & 0xFFFF0000u); }

static __device__ __forceinline__ v2f vfma(v2f a, v2f b, v2f c) {
    return __builtin_elementwise_fma(a, b, c);   // -> v_pk_fma_f32
}
static __device__ __forceinline__ v2f vbc(float s) { v2f r = {s, s}; return r; }

// ============ setup: direct-scatter CSR build ============
// Degrees via global atomics (1.6M RMWs over 100K addrs = ~16/addr, low
// contention); node-granular exclusive scan of indeg -> offs; records
// written DIRECTLY to final CSR slot via offs[c]+atomicAdd(cur[c]).
// Replaces the two-phase bucket sort (saves ~85MB of staging traffic).

__global__ __launch_bounds__(256) void k_count(const int* __restrict__ ei,
                                               const float* __restrict__ x,
                                               int* __restrict__ deg,
                                               int* __restrict__ indeg,
                                               ushort* __restrict__ xb) {
    const int gstep = NB_HIST * 256;
    const int gt = blockIdx.x * 256 + threadIdx.x;
    for (int e = gt; e < NE; e += gstep) {
        atomicAdd(&deg[ei[e]], 1);
        atomicAdd(&indeg[ei[NE + e]], 1);
    }
    // fused fp32 -> bf16 convert of x (independent work, saves a launch)
    for (int i = gt; i < NN * DIM / 4; i += gstep) {
        float4 v = ((const float4*)x)[i];
        ushort4 o = {f2bf(v.x), f2bf(v.y), f2bf(v.z), f2bf(v.w)};
        ((ushort4*)xb)[i] = o;
    }
}

// per-256-node-block exclusive scan of indeg; offs gets local excl, blockSum
__global__ __launch_bounds__(256) void k_scanA(const int* __restrict__ indeg,
                                               int* __restrict__ offs,
                                               int* __restrict__ blockSum) {
    __shared__ int s[256];
    int tid = threadIdx.x, b = blockIdx.x;
    int node = b * 256 + tid;
    int v = (node < NN) ? indeg[node] : 0;
    s[tid] = v;
    __syncthreads();
    for (int d = 1; d < 256; d <<= 1) {
        int a = (tid >= d) ? s[tid - d] : 0;
        __syncthreads();
        s[tid] += a;
        __syncthreads();
    }
    if (node < NN) offs[node] = s[tid] - v;
    if (tid == 255) blockSum[b] = s[255];
}

// scan the 391 block sums -> exclusive block bases
__global__ __launch_bounds__(512) void k_scanB(const int* __restrict__ blockSum,
                                               int* __restrict__ blockBase) {
    __shared__ int s[512];
    int tid = threadIdx.x;
    int v = (tid < NBUCK) ? blockSum[tid] : 0;
    s[tid] = v;
    __syncthreads();
    for (int d = 1; d < 512; d <<= 1) {
        int a = (tid >= d) ? s[tid - d] : 0;
        __syncthreads();
        s[tid] += a;
        __syncthreads();
    }
    if (tid < NBUCK) blockBase[tid] = s[tid] - v;
}

// finalize offs (+base), zero cur, compute dinv = rsqrt(deg+1)
__global__ __launch_bounds__(256) void k_scanC(const int* __restrict__ deg,
                                               const int* __restrict__ blockBase,
                                               int* __restrict__ offs,
                                               int* __restrict__ cur,
                                               float* __restrict__ dinv) {
    int b = blockIdx.x, tid = threadIdx.x;
    int node = b * 256 + tid;
    if (node < NN) {
        offs[node] += blockBase[b];
        cur[node] = 0;
        dinv[node] = rsqrtf((float)deg[node] + 1.0f);
    }
    if (b == NBUCK - 1 && tid == 0) offs[NN] = NE;
}

// record: {norm, bf16(ea0)|bf16(ea1), bf16(ea2)|0, row} -> direct to CSR slot
__global__ __launch_bounds__(256) void k_scat(const int* __restrict__ ei,
                                              const float* __restrict__ ea,
                                              const float* __restrict__ dinv,
                                              const int* __restrict__ offs,
                                              int* __restrict__ cur,
                                              uint4* __restrict__ csr) {
    const int gstep = NB_HIST * 256;
    const int gt = blockIdx.x * 256 + threadIdx.x;
    for (int e = gt; e < NE; e += gstep) {
        int r = ei[e];
        int c = ei[NE + e];
        uint4 rec;
        rec.x = __float_as_uint(dinv[r] * dinv[c]);
        rec.y = ((uint)f2bf(ea[e * 3]) << 16) | (uint)f2bf(ea[e * 3 + 1]);
        rec.z = ((uint)f2bf(ea[e * 3 + 2]) << 16);
        rec.w = (uint)r;
        int pos = offs[c] + atomicAdd(&cur[c], 1);
        csr[pos] = rec;
    }
}

// ---------------- fused BN-fold + weight prep ----------------
// grid 256 x 128. Blocks 0..127: Wt row n (bf16, transposed, A-scaled).
// Blocks 128..255: beff col j. All blocks: zero a 64-elem slice of snext.
// Stats arrive as NREP replica slots; the fold sums replicas (L2-resident).

__global__ __launch_bounds__(128) void k_prep(const float* __restrict__ W,
                                              const float* __restrict__ b,
                                              const float* __restrict__ g,
                                              const float* __restrict__ bt,
                                              const float* __restrict__ sprev,
                                              float* __restrict__ snext,
                                              int mode,
                                              ushort* __restrict__ Wt,
                                              float* __restrict__ beff) {
    __shared__ float s[DIM];
    int k = threadIdx.x;
    // zero next-layer stats replicas: 256 blocks x 64 elems = NREP*256
    if (k < 64) snext[blockIdx.x * 64 + k] = 0.0f;
    float A = 1.0f, B = 0.0f;
    if (mode) {
        float sm = 0.0f, sq = 0.0f;
        for (int r = 0; r < NREP; ++r) {
            sm += sprev[r * 256 + k];
            sq += sprev[r * 256 + 128 + k];
        }
        float m = sm * (1.0f / NN);
        float var = sq * (1.0f / NN) - m * m;
        float rs = rsqrtf(var + BN_EPS);
        A = rs * g[k];
        B = bt[k] - m * A;
    }
    if (blockIdx.x < DIM) {
        int n = blockIdx.x;
        Wt[n * DIM + k] = f2bf(A * W[k * DIM + n]);
    } else {
        int j = blockIdx.x - DIM;
        s[k] = B * W[k * DIM + j];
        __syncthreads();
        for (int d = 64; d > 0; d >>= 1) {
            if (k < d) s[k] += s[k + d];
            __syncthreads();
        }
        if (k == 0) beff[j] = b[j] + s[0];
    }
}

// ---------------- MFMA GEMM: Y[M,128] = A_bf[M,128] @ W + beff ----------------
// C/D: col = lane&15, row = quad*4 + reg  [measured: learn_hip m89/m91]

#define GEMM_MFMA_BODY(Abf, Wt)                                                     \
    const int lane = threadIdx.x & 63;                                              \
    const int wv   = threadIdx.x >> 6;                                              \
    const int m    = lane & 15;                                                     \
    const int quad = lane >> 4;                                                     \
    const int row0 = blockIdx.x * 64 + wv * 16;                                     \
    const int rr   = min(row0 + m, NN - 1);                                         \
    const short8* ap = (const short8*)&Abf[(size_t)rr * DIM + quad * 8];            \
    short8 a0 = ap[0];                                                              \
    short8 a1 = ap[4];                                                              \
    short8 a2 = ap[8];                                                              \
    short8 a3 = ap[12];                                                             \
    f32x4 acc[8];                                                                   \
    _Pragma("unroll")                                                               \
    for (int nt = 0; nt < 8; ++nt) {                                                \
        const short8* bp = (const short8*)&Wt[(size_t)(nt * 16 + m) * DIM + quad * 8]; \
        f32x4 c = {0.f, 0.f, 0.f, 0.f};                                             \
        c = __builtin_amdgcn_mfma_f32_16x16x32_bf16(a0, bp[0],  c, 0, 0, 0);        \
        c = __builtin_amdgcn_mfma_f32_16x16x32_bf16(a1, bp[4],  c, 0, 0, 0);        \
        c = __builtin_amdgcn_mfma_f32_16x16x32_bf16(a2, bp[8],  c, 0, 0, 0);        \
        c = __builtin_amdgcn_mfma_f32_16x16x32_bf16(a3, bp[12], c, 0, 0, 0);        \
        acc[nt] = c;                                                                \
    }                                                                               \
    const int rbase = row0 + quad * 4;

__global__ __launch_bounds__(256) void k_gemm_mf_bf(const ushort* __restrict__ Abf,
                                                    const ushort* __restrict__ Wt,
                                                    const float* __restrict__ beff,
                                                    ushort* __restrict__ Y) {
    GEMM_MFMA_BODY(Abf, Wt)
#pragma unroll
    for (int nt = 0; nt < 8; ++nt) {
        int col = nt * 16 + m;
        float bb = beff[col];
#pragma unroll
        for (int i = 0; i < 4; ++i) {
            int row = rbase + i;
            if (row < NN) Y[(size_t)row * DIM + col] = f2bf(acc[nt][i] + bb);
        }
    }
}

__global__ __launch_bounds__(256) void k_gemm_mf_f32(const ushort* __restrict__ Abf,
                                                     const ushort* __restrict__ Wt,
                                                     const float* __restrict__ beff,
                                                     float* __restrict__ Y) {
    GEMM_MFMA_BODY(Abf, Wt)
#pragma unroll
    for (int nt = 0; nt < 8; ++nt) {
        int col = nt * 16 + m;
        float bb = beff[col];
#pragma unroll
        for (int i = 0; i < 4; ++i) {
            int row = rbase + i;
            if (row < NN) Y[(size_t)row * DIM + col] = acc[nt][i] + bb;
        }
    }
}

// ---------------- aggregation + fused BN statistics ----------------
// wave processes 4 nodes; 8 edges/iter (lane = q*16 + oc, 4 edge-quads x 2).
// 2-deep software pipeline. BN partials merged per block in LDS, then one
// atomicAdd per thread into a REPLICA slot (blockIdx&63).

static __device__ __forceinline__ void edge_compute(float4 r, float4 hv, float n,
                                                    const v2f* __restrict__ w0,
                                                    const v2f* __restrict__ w1,
                                                    const v2f* __restrict__ w2,
                                                    const v2f* __restrict__ vbe,
                                                    v2f* __restrict__ acc) {
    uint py = __float_as_uint(r.y), pz = __float_as_uint(r.z);
    v2f va0 = vbc(bf_hi(py)), va1 = vbc(bf_lo(py)), va2 = vbc(bf_hi(pz));
    v2f vn = vbc(n);
    uint hx = __float_as_uint(hv.x), hy = __float_as_uint(hv.y);
    uint hz = __float_as_uint(hv.z), hw = __float_as_uint(hv.w);
    v2f hp[4] = {{bf_lo(hx), bf_hi(hx)}, {bf_lo(hy), bf_hi(hy)},
                 {bf_lo(hz), bf_hi(hz)}, {bf_lo(hw), bf_hi(hw)}};
    const v2f z = {0.0f, 0.0f};
#pragma unroll
    for (int j = 0; j < 4; ++j) {
        v2f e = vfma(va2, w2[j], vbe[j]);
        e = vfma(va1, w1[j], e);
        e = vfma(va0, w0[j], e);
        v2f u = hp[j] + e;
        u = __builtin_elementwise_max(u, z);   // v_pk_max_f32
        acc[j] = vfma(vn, u, acc[j]);
    }
}

__global__ __launch_bounds__(256) void k_agg(const float4* __restrict__ h4,
                                             const float4* __restrict__ csr,
                                             const int* __restrict__ offs,
                                             const float* __restrict__ We,
                                             const float* __restrict__ be,
                                             uint* __restrict__ tb,
                                             float* __restrict__ stats) {
    __shared__ float pbuf[4][256];
    int wv = threadIdx.x >> 6;
    int lane = threadIdx.x & 63;
    int q  = lane >> 4;
    int oc = lane & 15;
    int j0 = oc * 8;

    float4 t0, t1;
    t0 = *(const float4*)&We[j0];             t1 = *(const float4*)&We[j0 + 4];
    v2f w0[4] = {{t0.x, t0.y}, {t0.z, t0.w}, {t1.x, t1.y}, {t1.z, t1.w}};
    t0 = *(const float4*)&We[DIM + j0];       t1 = *(const float4*)&We[DIM + j0 + 4];
    v2f w1[4] = {{t0.x, t0.y}, {t0.z, t0.w}, {t1.x, t1.y}, {t1.z, t1.w}};
    t0 = *(const float4*)&We[2 * DIM + j0];   t1 = *(const float4*)&We[2 * DIM + j0 + 4];
    v2f w2[4] = {{t0.x, t0.y}, {t0.z, t0.w}, {t1.x, t1.y}, {t1.z, t1.w}};
    t0 = *(const float4*)&be[j0];             t1 = *(const float4*)&be[j0 + 4];
    v2f vbe[4] = {{t0.x, t0.y}, {t0.z, t0.w}, {t1.x, t1.y}, {t1.z, t1.w}};

    v2f smv[4] = {{0,0},{0,0},{0,0},{0,0}};
    v2f sqv[4] = {{0,0},{0,0},{0,0},{0,0}};

    const int v0 = blockIdx.x * 16 + wv * 4;     // NBLK_AGG*16 == NN exactly
    int ofs[5];
#pragma unroll
    for (int k = 0; k < 5; ++k) ofs[k] = offs[v0 + k];

    for (int it = 0; it < 4; ++it) {
        int v = v0 + it;
        v2f acc[4] = {{0,0},{0,0},{0,0},{0,0}};
        int s0 = ofs[it], e0 = ofs[it + 1];

        // pipeline prologue: issue csr for iter0 AND iter1 together, then
        // h gathers for iter0 (rA wait is the only exposed latency per node)
        float4 rA1 = csr[s0 + q];
        float4 rA2 = csr[s0 + 4 + q];
        float4 rB1 = csr[s0 + 8 + q];
        float4 rB2 = csr[s0 + 12 + q];
        float4 hA1 = h4[(size_t)__float_as_int(rA1.w) * 16 + oc];
        float4 hA2 = h4[(size_t)__float_as_int(rA2.w) * 16 + oc];

#pragma unroll 2
        for (int base = s0; base < e0; base += 8) {
            // stage B: rows -> issue h(B); issue csr(C)
            float4 hB1 = h4[(size_t)__float_as_int(rB1.w) * 16 + oc];
            float4 hB2 = h4[(size_t)__float_as_int(rB2.w) * 16 + oc];
            float4 rC1 = csr[base + 16 + q];
            float4 rC2 = csr[base + 20 + q];
            // stage A compute (hA issued one iteration ago)
            float n1 = (base + q < e0) ? rA1.x : 0.0f;
            float n2 = (base + 4 + q < e0) ? rA2.x : 0.0f;
            edge_compute(rA1, hA1, n1, w0, w1, w2, vbe, acc);
            edge_compute(rA2, hA2, n2, w0, w1, w2, vbe, acc);
            rA1 = rB1; rA2 = rB2; rB1 = rC1; rB2 = rC2;
            hA1 = hB1; hA2 = hB2;
        }

        // reduce across the 4 edge-quads (lanes with equal oc)
#pragma unroll
        for (int j = 0; j < 4; ++j) {
            acc[j].x += __shfl_xor(acc[j].x, 16); acc[j].x += __shfl_xor(acc[j].x, 32);
            acc[j].y += __shfl_xor(acc[j].y, 16); acc[j].y += __shfl_xor(acc[j].y, 32);
        }

        if (q == 0) {
            uint4 pk;
            uint pw[4];
#pragma unroll
            for (int j = 0; j < 4; ++j) {
                acc[j].x = fmaxf(acc[j].x, 0.0f);   // outer relu
                acc[j].y = fmaxf(acc[j].y, 0.0f);
                smv[j] = smv[j] + acc[j];
                sqv[j] = vfma(acc[j], acc[j], sqv[j]);
                pw[j] = ((uint)f2bf(acc[j].y) << 16) | f2bf(acc[j].x);
            }
            pk.x = pw[0]; pk.y = pw[1]; pk.z = pw[2]; pk.w = pw[3];
            *(uint4*)&tb[(size_t)v * 64 + oc * 4] = pk;
        }
    }

    if (q == 0) {
#pragma unroll
        for (int j = 0; j < 4; ++j) {
            pbuf[wv][j0 + 2 * j]       = smv[j].x;
            pbuf[wv][j0 + 2 * j + 1]   = smv[j].y;
            pbuf[wv][128 + j0 + 2 * j]     = sqv[j].x;
            pbuf[wv][128 + j0 + 2 * j + 1] = sqv[j].y;
        }
    }
    __syncthreads();
    int tid = threadIdx.x;
    float s = pbuf[0][tid] + pbuf[1][tid] + pbuf[2][tid] + pbuf[3][tid];
    atomicAdd(&stats[(blockIdx.x & (NREP - 1)) * 256 + tid], s);
}

// ---------------- launch ----------------

static inline char* alignp(char* p, size_t a) {
    return (char*)(((uintptr_t)p + a - 1) & ~(uintptr_t)(a - 1));
}

extern "C" void kernel_launch(void* const* d_in, const int* in_sizes, int n_in,
                              void* d_out, int out_size, void* d_ws, size_t ws_size,
                              hipStream_t stream) {
    const float* x   = (const float*)d_in[0];
    const int*   ei  = (const int*)d_in[1];
    const float* ea  = (const float*)d_in[2];
    const float* Wp[3]  = {(const float*)d_in[3],  (const float*)d_in[9],  (const float*)d_in[15]};
    const float* bp[3]  = {(const float*)d_in[4],  (const float*)d_in[10], (const float*)d_in[16]};
    const float* Wep[3] = {(const float*)d_in[5],  (const float*)d_in[11], (const float*)d_in[17]};
    const float* bep[3] = {(const float*)d_in[6],  (const float*)d_in[12], (const float*)d_in[18]};
    const float* gp[3]  = {(const float*)d_in[7],  (const float*)d_in[13], (const float*)d_in[19]};
    const float* btp[3] = {(const float*)d_in[8],  (const float*)d_in[14], (const float*)d_in[20]};
    const float* Wl  = (const float*)d_in[21];
    const float* bl  = (const float*)d_in[22];
    float* out = (float*)d_out;

    char* p = (char*)d_ws;
    auto alloc = [&](size_t bytes) -> void* {
        p = alignp(p, 256);
        void* r = (void*)p;
        p += bytes;
        return r;
    };

    int*    degs     = (int*)alloc(2 * NN * sizeof(int));   // deg | indeg (one memset)
    int*    deg      = degs;
    int*    indeg    = degs + NN;
    int*    cur      = (int*)alloc(NN * sizeof(int));
    int*    blockSum = (int*)alloc(NBUCK * sizeof(int));
    int*    blockBase= (int*)alloc(NBUCK * sizeof(int));
    int*    offs     = (int*)alloc((NN + 1) * sizeof(int));
    float*  dinv     = (float*)alloc(NN * sizeof(float));
    uint4*  csr      = (uint4*)alloc(((size_t)NE + CSR_PAD) * sizeof(uint4));
    ushort* x_bf     = (ushort*)alloc((size_t)NN * DIM * sizeof(ushort));
    ushort* h_bf     = (ushort*)alloc((size_t)NN * DIM * sizeof(ushort));
    ushort* t_bf     = (ushort*)alloc((size_t)NN * DIM * sizeof(ushort));
    ushort* Wt       = (ushort*)alloc(DIM * DIM * sizeof(ushort));
    float*  beff     = (float*)alloc(DIM * sizeof(float));
    float*  sb0      = (float*)alloc((size_t)NREP * 256 * sizeof(float));
    float*  sb1      = (float*)alloc((size_t)NREP * 256 * sizeof(float));

    hipMemsetAsync(degs, 0, 2 * NN * sizeof(int), stream);
    hipMemsetAsync(csr + NE, 0, CSR_PAD * sizeof(uint4), stream);  // zero-norm pad
    k_count<<<NB_HIST, 256, 0, stream>>>(ei, x, deg, indeg, x_bf);
    k_scanA<<<NBUCK, 256, 0, stream>>>(indeg, offs, blockSum);
    k_scanB<<<1, 512, 0, stream>>>(blockSum, blockBase);
    k_scanC<<<NBUCK, 256, 0, stream>>>(deg, blockBase, offs, cur, dinv);
    k_scat<<<NB_HIST, 256, 0, stream>>>(ei, ea, dinv, offs, cur, csr);

    // stats double-buffer: scur(l) = (l&1)? sb1 : sb0; sprev(l) = the other.
    float* sbs[2] = {sb0, sb1};
    const ushort* Xbf = x_bf;
    for (int l = 0; l < 3; ++l) {
        float* scur = sbs[l & 1];
        float* sprev = sbs[(l + 1) & 1];
        const float* gg = (l == 0) ? gp[0] : gp[l - 1];
        const float* bb = (l == 0) ? btp[0] : btp[l - 1];
        k_prep<<<256, 128, 0, stream>>>(Wp[l], bp[l], gg, bb, sprev, scur,
                                        (l == 0) ? 0 : 1, Wt, beff);
        k_gemm_mf_bf<<<NBLK_GEMM, 256, 0, stream>>>(Xbf, Wt, beff, h_bf);
        k_agg<<<NBLK_AGG, 256, 0, stream>>>((const float4*)h_bf, (const float4*)csr, offs,
                                            Wep[l], bep[l], (uint*)t_bf, scur);
        Xbf = t_bf;
    }

    // final linear: BN3 folded (stats in scur(2) = sb0)
    k_prep<<<256, 128, 0, stream>>>(Wl, bl, gp[2], btp[2], sb0, sb1, 1, Wt, beff);
    k_gemm_mf_f32<<<NBLK_GEMM, 256, 0, stream>>>(t_bf, Wt, beff, out);
}

// Round 9
// 694.635 us; speedup vs baseline: 1.1562x; 1.1562x over previous
//
#include <hip/hip_runtime.h>
#include <stdint.h>

#define NN 100000
#define NE 1600000
#define DIM 128
#define BN_EPS 1e-5f
#define NBUCK 391               // ceil(NN/256) col/row buckets of 256 nodes
#define NBLK_GEMM 1563          // ceil(100000/64)
#define NBLK_AGG 6250           // 16 nodes/block: 4 waves x 4 nodes
#define NB_HIST 512             // grid for grid-strided histogram/scatter kernels
#define CSR_PAD 32              // zero-norm pad records past NE (2-deep prefetch)
#define NREP 64                 // stats replica slots (contention: 6250/64 ~= 98 per addr)

typedef unsigned int uint;
typedef unsigned short ushort;
typedef unsigned char uchar;
typedef __attribute__((ext_vector_type(8))) short short8;   // 8 x bf16 (4 VGPRs)
typedef __attribute__((ext_vector_type(4))) float f32x4;
typedef __attribute__((ext_vector_type(2))) float v2f;      // packed fp32 pair

// ---------------- bf16 helpers ----------------

static __device__ __forceinline__ ushort f2bf(float f) {
    uint u = __float_as_uint(f);
    u += 0x7FFF + ((u >> 16) & 1);   // round-to-nearest-even
    return (ushort)(u >> 16);
}
static __device__ __forceinline__ float bf_lo(uint p) { return __uint_as_float(p << 16); }
static __device__ __forceinline__ float bf_hi(uint p) { return __uint_as_float(p & 0xFFFF0000u); }

static __device__ __forceinline__ v2f vfma(v2f a, v2f b, v2f c) {
    return __builtin_elementwise_fma(a, b, c);   // -> v_pk_fma_f32
}
static __device__ __forceinline__ v2f vbc(float s) { v2f r = {s, s}; return r; }

// ============ setup: bucket-sort CSR build ============
// LDS-aggregated histograms (round-8 lesson: device-scope atomics cost ~39B
// fabric-write each at ~27G/s -- LDS hist + per-bucket flush is far cheaper).
// Row and col scatters merged into ONE edge pass (k_scat); norm is filled in
// later by k_sort_col once dinv exists.

__global__ __launch_bounds__(256) void k_count(const int* __restrict__ ei,
                                               int* __restrict__ rowCnt,
                                               int* __restrict__ colCnt) {
    __shared__ int hr[NBUCK], hc[NBUCK];
    int tid = threadIdx.x;
    for (int b = tid; b < NBUCK; b += 256) { hr[b] = 0; hc[b] = 0; }
    __syncthreads();
    const int gstep = NB_HIST * 256;
    const int gt = blockIdx.x * 256 + tid;
    for (int e = gt; e < NE; e += gstep) {
        atomicAdd(&hr[ei[e] >> 8], 1);
        atomicAdd(&hc[ei[NE + e] >> 8], 1);
    }
    __syncthreads();
    for (int b = tid; b < NBUCK; b += 256) {
        if (hr[b]) atomicAdd(&rowCnt[b], hr[b]);
        if (hc[b]) atomicAdd(&colCnt[b], hc[b]);
    }
}

__global__ __launch_bounds__(512) void k_scanb(const int* __restrict__ rowCnt,
                                               const int* __restrict__ colCnt,
                                               int* __restrict__ rowBase,
                                               int* __restrict__ colBase,
                                               int* __restrict__ rowCur,
                                               int* __restrict__ colCur) {
    __shared__ int s[512];
    int tid = threadIdx.x;
    int v = (tid < NBUCK) ? rowCnt[tid] : 0;
    s[tid] = v;
    __syncthreads();
    for (int d = 1; d < 512; d <<= 1) {
        int a = (tid >= d) ? s[tid - d] : 0;
        __syncthreads();
        s[tid] += a;
        __syncthreads();
    }
    if (tid < NBUCK) { int e = s[tid] - v; rowBase[tid] = e; rowCur[tid] = e; }
    if (tid == NBUCK) rowBase[NBUCK] = s[NBUCK];
    __syncthreads();
    v = (tid < NBUCK) ? colCnt[tid] : 0;
    s[tid] = v;
    __syncthreads();
    for (int d = 1; d < 512; d <<= 1) {
        int a = (tid >= d) ? s[tid - d] : 0;
        __syncthreads();
        s[tid] += a;
        __syncthreads();
    }
    if (tid < NBUCK) { int e = s[tid] - v; colBase[tid] = e; colCur[tid] = e; }
    if (tid == NBUCK) colBase[NBUCK] = s[NBUCK];
}

// merged row+col scatter: one edge pass writes rowScat bytes AND col records
// (norm slot left 0 -- filled by k_sort_col after dinv exists).
__global__ __launch_bounds__(256) void k_scat(const int* __restrict__ ei,
                                              const float* __restrict__ ea,
                                              int* __restrict__ rowCur,
                                              int* __restrict__ colCur,
                                              uchar* __restrict__ rowScat,
                                              uint4* __restrict__ tmp) {
    __shared__ int hr[NBUCK], hc[NBUCK], lbr[NBUCK], lbc[NBUCK], lcr[NBUCK], lcc[NBUCK];
    int tid = threadIdx.x;
    for (int b = tid; b < NBUCK; b += 256) { hr[b] = 0; hc[b] = 0; lcr[b] = 0; lcc[b] = 0; }
    __syncthreads();
    const int gstep = NB_HIST * 256;
    const int gt = blockIdx.x * 256 + tid;
    for (int e = gt; e < NE; e += gstep) {
        atomicAdd(&hr[ei[e] >> 8], 1);
        atomicAdd(&hc[ei[NE + e] >> 8], 1);
    }
    __syncthreads();
    for (int b = tid; b < NBUCK; b += 256) {
        lbr[b] = hr[b] ? atomicAdd(&rowCur[b], hr[b]) : 0;
        lbc[b] = hc[b] ? atomicAdd(&colCur[b], hc[b]) : 0;
    }
    __syncthreads();
    for (int e = gt; e < NE; e += gstep) {
        int r = ei[e];
        int c = ei[NE + e];
        int posr = lbr[r >> 8] + atomicAdd(&lcr[r >> 8], 1);
        rowScat[posr] = (uchar)(r & 255);
        uint4 rec;
        rec.x = 0u;                                   // norm filled in k_sort_col
        rec.y = ((uint)f2bf(ea[e * 3]) << 16) | (uint)f2bf(ea[e * 3 + 1]);
        rec.z = ((uint)f2bf(ea[e * 3 + 2]) << 16) | (uint)(c & 255);
        rec.w = (uint)r;
        int posc = lbc[c >> 8] + atomicAdd(&lcc[c >> 8], 1);
        tmp[posc] = rec;
    }
}

__global__ __launch_bounds__(1024) void k_deg(const uchar* __restrict__ rowScat,
                                              const int* __restrict__ rowBase,
                                              float* __restrict__ dinv) {
    __shared__ int h[256];
    int tid = threadIdx.x;
    int b = blockIdx.x;
    if (tid < 256) h[tid] = 0;
    __syncthreads();
    int base = rowBase[b], cnt = rowBase[b + 1] - base;
    for (int i = tid; i < cnt; i += 1024) atomicAdd(&h[rowScat[base + i]], 1);
    __syncthreads();
    if (tid < 256) {
        int node = b * 256 + tid;
        if (node < NN) dinv[node] = rsqrtf((float)h[tid] + 1.0f);
    }
}

// per-bucket fine sort -> csr + offs; fills norm = dinv[row]*dinv[col]
__global__ __launch_bounds__(1024) void k_sort_col(const uint4* __restrict__ tmp,
                                                   const int* __restrict__ colBase,
                                                   const float* __restrict__ dinv,
                                                   uint4* __restrict__ csr,
                                                   int* __restrict__ offs) {
    __shared__ int hh[256], sc[256], cur[256];
    __shared__ float dloc[256];
    int tid = threadIdx.x;
    int b = blockIdx.x;
    if (tid < 256) {
        hh[tid] = 0;
        int node = b * 256 + tid;
        dloc[tid] = (node < NN) ? dinv[node] : 0.0f;
    }
    __syncthreads();
    int base = colBase[b], cnt = colBase[b + 1] - base;
    for (int i = tid; i < cnt; i += 1024) atomicAdd(&hh[tmp[base + i].z & 255], 1);
    __syncthreads();
    int v = 0;
    if (tid < 256) { v = hh[tid]; sc[tid] = v; }
    __syncthreads();
    for (int d = 1; d < 256; d <<= 1) {
        int add = 0;
        if (tid < 256 && tid >= d) add = sc[tid - d];
        __syncthreads();
        if (tid < 256) sc[tid] += add;
        __syncthreads();
    }
    if (tid < 256) {
        int excl = sc[tid] - v;
        int node = b * 256 + tid;
        if (node < NN) offs[node] = base + excl;
        if (b == NBUCK - 1 && tid == 0) offs[NN] = NE;
        cur[tid] = excl;
    }
    __syncthreads();
    for (int i = tid; i < cnt; i += 1024) {
        uint4 rec = tmp[base + i];
        int f = rec.z & 255;
        rec.x = __float_as_uint(dinv[(int)rec.w] * dloc[f]);
        int pos = atomicAdd(&cur[f], 1);
        csr[base + pos] = rec;
    }
}

// ---------------- fused BN-fold + weight prep ----------------
// grid 256 x 128. Blocks 0..127: Wt row n (bf16, transposed, A-scaled).
// Blocks 128..255: beff col j. All blocks: zero a 64-elem slice of snext.
// Stats arrive as NREP replica slots; the fold sums replicas (L2-resident).

__global__ __launch_bounds__(128) void k_prep(const float* __restrict__ W,
                                              const float* __restrict__ b,
                                              const float* __restrict__ g,
                                              const float* __restrict__ bt,
                                              const float* __restrict__ sprev,
                                              float* __restrict__ snext,
                                              int mode,
                                              ushort* __restrict__ Wt,
                                              float* __restrict__ beff) {
    __shared__ float s[DIM];
    int k = threadIdx.x;
    // zero next-layer stats replicas: 256 blocks x 64 elems = NREP*256
    if (k < 64) snext[blockIdx.x * 64 + k] = 0.0f;
    float A = 1.0f, B = 0.0f;
    if (mode) {
        float sm = 0.0f, sq = 0.0f;
        for (int r = 0; r < NREP; ++r) {
            sm += sprev[r * 256 + k];
            sq += sprev[r * 256 + 128 + k];
        }
        float m = sm * (1.0f / NN);
        float var = sq * (1.0f / NN) - m * m;
        float rs = rsqrtf(var + BN_EPS);
        A = rs * g[k];
        B = bt[k] - m * A;
    }
    if (blockIdx.x < DIM) {
        int n = blockIdx.x;
        Wt[n * DIM + k] = f2bf(A * W[k * DIM + n]);
    } else {
        int j = blockIdx.x - DIM;
        s[k] = B * W[k * DIM + j];
        __syncthreads();
        for (int d = 64; d > 0; d >>= 1) {
            if (k < d) s[k] += s[k + d];
            __syncthreads();
        }
        if (k == 0) beff[j] = b[j] + s[0];
    }
}

// ---------------- MFMA GEMM: Y[M,128] = A[M,128] @ W + beff ----------------
// C/D: col = lane&15, row = quad*4 + reg  [measured: learn_hip m89/m91]

#define GEMM_MFMA_CORE(a0, a1, a2, a3, Wt)                                          \
    f32x4 acc[8];                                                                   \
    _Pragma("unroll")                                                               \
    for (int nt = 0; nt < 8; ++nt) {                                                \
        const short8* bp = (const short8*)&Wt[(size_t)(nt * 16 + m) * DIM + quad * 8]; \
        f32x4 c = {0.f, 0.f, 0.f, 0.f};                                             \
        c = __builtin_amdgcn_mfma_f32_16x16x32_bf16(a0, bp[0],  c, 0, 0, 0);        \
        c = __builtin_amdgcn_mfma_f32_16x16x32_bf16(a1, bp[4],  c, 0, 0, 0);        \
        c = __builtin_amdgcn_mfma_f32_16x16x32_bf16(a2, bp[8],  c, 0, 0, 0);        \
        c = __builtin_amdgcn_mfma_f32_16x16x32_bf16(a3, bp[12], c, 0, 0, 0);        \
        acc[nt] = c;                                                                \
    }                                                                               \
    const int rbase = row0 + quad * 4;

#define GEMM_LANE_SETUP                                                             \
    const int lane = threadIdx.x & 63;                                              \
    const int wv   = threadIdx.x >> 6;                                              \
    const int m    = lane & 15;                                                     \
    const int quad = lane >> 4;                                                     \
    const int row0 = blockIdx.x * 64 + wv * 16;                                     \
    const int rr   = min(row0 + m, NN - 1);

static __device__ __forceinline__ short8 cvt8(float4 a, float4 b) {
    short8 r;
    r[0] = (short)f2bf(a.x); r[1] = (short)f2bf(a.y);
    r[2] = (short)f2bf(a.z); r[3] = (short)f2bf(a.w);
    r[4] = (short)f2bf(b.x); r[5] = (short)f2bf(b.y);
    r[6] = (short)f2bf(b.z); r[7] = (short)f2bf(b.w);
    return r;
}

// layer-1: A is fp32 (input x), converted in-register (same f2bf as before ->
// bit-identical to the old x2bf+bf-GEMM path; saves 51MB of x_bf round-trip)
__global__ __launch_bounds__(256) void k_gemm_mf_f32in(const float* __restrict__ Af,
                                                       const ushort* __restrict__ Wt,
                                                       const float* __restrict__ beff,
                                                       ushort* __restrict__ Y) {
    GEMM_LANE_SETUP
    const float4* apf = (const float4*)&Af[(size_t)rr * DIM] + quad * 2;
    short8 a0 = cvt8(apf[0],  apf[1]);
    short8 a1 = cvt8(apf[8],  apf[9]);
    short8 a2 = cvt8(apf[16], apf[17]);
    short8 a3 = cvt8(apf[24], apf[25]);
    GEMM_MFMA_CORE(a0, a1, a2, a3, Wt)
#pragma unroll
    for (int nt = 0; nt < 8; ++nt) {
        int col = nt * 16 + m;
        float bb = beff[col];
#pragma unroll
        for (int i = 0; i < 4; ++i) {
            int row = rbase + i;
            if (row < NN) Y[(size_t)row * DIM + col] = f2bf(acc[nt][i] + bb);
        }
    }
}

__global__ __launch_bounds__(256) void k_gemm_mf_bf(const ushort* __restrict__ Abf,
                                                    const ushort* __restrict__ Wt,
                                                    const float* __restrict__ beff,
                                                    ushort* __restrict__ Y) {
    GEMM_LANE_SETUP
    const short8* ap = (const short8*)&Abf[(size_t)rr * DIM + quad * 8];
    short8 a0 = ap[0];
    short8 a1 = ap[4];
    short8 a2 = ap[8];
    short8 a3 = ap[12];
    GEMM_MFMA_CORE(a0, a1, a2, a3, Wt)
#pragma unroll
    for (int nt = 0; nt < 8; ++nt) {
        int col = nt * 16 + m;
        float bb = beff[col];
#pragma unroll
        for (int i = 0; i < 4; ++i) {
            int row = rbase + i;
            if (row < NN) Y[(size_t)row * DIM + col] = f2bf(acc[nt][i] + bb);
        }
    }
}

__global__ __launch_bounds__(256) void k_gemm_mf_f32(const ushort* __restrict__ Abf,
                                                     const ushort* __restrict__ Wt,
                                                     const float* __restrict__ beff,
                                                     float* __restrict__ Y) {
    GEMM_LANE_SETUP
    const short8* ap = (const short8*)&Abf[(size_t)rr * DIM + quad * 8];
    short8 a0 = ap[0];
    short8 a1 = ap[4];
    short8 a2 = ap[8];
    short8 a3 = ap[12];
    GEMM_MFMA_CORE(a0, a1, a2, a3, Wt)
#pragma unroll
    for (int nt = 0; nt < 8; ++nt) {
        int col = nt * 16 + m;
        float bb = beff[col];
#pragma unroll
        for (int i = 0; i < 4; ++i) {
            int row = rbase + i;
            if (row < NN) Y[(size_t)row * DIM + col] = acc[nt][i] + bb;
        }
    }
}

// ---------------- aggregation + fused BN statistics ----------------
// wave processes 4 nodes; 8 edges/iter (lane = q*16 + oc, 4 edge-quads x 2).
// 2-deep software pipeline. BN partials merged per block in LDS, then one
// atomicAdd per thread into a REPLICA slot (blockIdx&63).

static __device__ __forceinline__ void edge_compute(float4 r, float4 hv, float n,
                                                    const v2f* __restrict__ w0,
                                                    const v2f* __restrict__ w1,
                                                    const v2f* __restrict__ w2,
                                                    const v2f* __restrict__ vbe,
                                                    v2f* __restrict__ acc) {
    uint py = __float_as_uint(r.y), pz = __float_as_uint(r.z);
    v2f va0 = vbc(bf_hi(py)), va1 = vbc(bf_lo(py)), va2 = vbc(bf_hi(pz));
    v2f vn = vbc(n);
    uint hx = __float_as_uint(hv.x), hy = __float_as_uint(hv.y);
    uint hz = __float_as_uint(hv.z), hw = __float_as_uint(hv.w);
    v2f hp[4] = {{bf_lo(hx), bf_hi(hx)}, {bf_lo(hy), bf_hi(hy)},
                 {bf_lo(hz), bf_hi(hz)}, {bf_lo(hw), bf_hi(hw)}};
    const v2f z = {0.0f, 0.0f};
#pragma unroll
    for (int j = 0; j < 4; ++j) {
        v2f e = vfma(va2, w2[j], vbe[j]);
        e = vfma(va1, w1[j], e);
        e = vfma(va0, w0[j], e);
        v2f u = hp[j] + e;
        u = __builtin_elementwise_max(u, z);   // v_pk_max_f32
        acc[j] = vfma(vn, u, acc[j]);
    }
}

__global__ __launch_bounds__(256) void k_agg(const float4* __restrict__ h4,
                                             const float4* __restrict__ csr,
                                             const int* __restrict__ offs,
                                             const float* __restrict__ We,
                                             const float* __restrict__ be,
                                             uint* __restrict__ tb,
                                             float* __restrict__ stats) {
    __shared__ float pbuf[4][256];
    int wv = threadIdx.x >> 6;
    int lane = threadIdx.x & 63;
    int q  = lane >> 4;
    int oc = lane & 15;
    int j0 = oc * 8;

    float4 t0, t1;
    t0 = *(const float4*)&We[j0];             t1 = *(const float4*)&We[j0 + 4];
    v2f w0[4] = {{t0.x, t0.y}, {t0.z, t0.w}, {t1.x, t1.y}, {t1.z, t1.w}};
    t0 = *(const float4*)&We[DIM + j0];       t1 = *(const float4*)&We[DIM + j0 + 4];
    v2f w1[4] = {{t0.x, t0.y}, {t0.z, t0.w}, {t1.x, t1.y}, {t1.z, t1.w}};
    t0 = *(const float4*)&We[2 * DIM + j0];   t1 = *(const float4*)&We[2 * DIM + j0 + 4];
    v2f w2[4] = {{t0.x, t0.y}, {t0.z, t0.w}, {t1.x, t1.y}, {t1.z, t1.w}};
    t0 = *(const float4*)&be[j0];             t1 = *(const float4*)&be[j0 + 4];
    v2f vbe[4] = {{t0.x, t0.y}, {t0.z, t0.w}, {t1.x, t1.y}, {t1.z, t1.w}};

    v2f smv[4] = {{0,0},{0,0},{0,0},{0,0}};
    v2f sqv[4] = {{0,0},{0,0},{0,0},{0,0}};

    const int v0 = blockIdx.x * 16 + wv * 4;     // NBLK_AGG*16 == NN exactly
    int ofs[5];
#pragma unroll
    for (int k = 0; k < 5; ++k) ofs[k] = offs[v0 + k];

    for (int it = 0; it < 4; ++it) {
        int v = v0 + it;
        v2f acc[4] = {{0,0},{0,0},{0,0},{0,0}};
        int s0 = ofs[it], e0 = ofs[it + 1];

        // pipeline prologue: issue csr for iter0 AND iter1 together, then
        // h gathers for iter0 (rA wait is the only exposed latency per node)
        float4 rA1 = csr[s0 + q];
        float4 rA2 = csr[s0 + 4 + q];
        float4 rB1 = csr[s0 + 8 + q];
        float4 rB2 = csr[s0 + 12 + q];
        float4 hA1 = h4[(size_t)__float_as_int(rA1.w) * 16 + oc];
        float4 hA2 = h4[(size_t)__float_as_int(rA2.w) * 16 + oc];

#pragma unroll 2
        for (int base = s0; base < e0; base += 8) {
            // stage B: rows -> issue h(B); issue csr(C)
            float4 hB1 = h4[(size_t)__float_as_int(rB1.w) * 16 + oc];
            float4 hB2 = h4[(size_t)__float_as_int(rB2.w) * 16 + oc];
            float4 rC1 = csr[base + 16 + q];
            float4 rC2 = csr[base + 20 + q];
            // stage A compute (hA issued one iteration ago)
            float n1 = (base + q < e0) ? rA1.x : 0.0f;
            float n2 = (base + 4 + q < e0) ? rA2.x : 0.0f;
            edge_compute(rA1, hA1, n1, w0, w1, w2, vbe, acc);
            edge_compute(rA2, hA2, n2, w0, w1, w2, vbe, acc);
            rA1 = rB1; rA2 = rB2; rB1 = rC1; rB2 = rC2;
            hA1 = hB1; hA2 = hB2;
        }

        // reduce across the 4 edge-quads (lanes with equal oc)
#pragma unroll
        for (int j = 0; j < 4; ++j) {
            acc[j].x += __shfl_xor(acc[j].x, 16); acc[j].x += __shfl_xor(acc[j].x, 32);
            acc[j].y += __shfl_xor(acc[j].y, 16); acc[j].y += __shfl_xor(acc[j].y, 32);
        }

        if (q == 0) {
            uint4 pk;
            uint pw[4];
#pragma unroll
            for (int j = 0; j < 4; ++j) {
                acc[j].x = fmaxf(acc[j].x, 0.0f);   // outer relu
                acc[j].y = fmaxf(acc[j].y, 0.0f);
                smv[j] = smv[j] + acc[j];
                sqv[j] = vfma(acc[j], acc[j], sqv[j]);
                pw[j] = ((uint)f2bf(acc[j].y) << 16) | f2bf(acc[j].x);
            }
            pk.x = pw[0]; pk.y = pw[1]; pk.z = pw[2]; pk.w = pw[3];
            *(uint4*)&tb[(size_t)v * 64 + oc * 4] = pk;
        }
    }

    if (q == 0) {
#pragma unroll
        for (int j = 0; j < 4; ++j) {
            pbuf[wv][j0 + 2 * j]       = smv[j].x;
            pbuf[wv][j0 + 2 * j + 1]   = smv[j].y;
            pbuf[wv][128 + j0 + 2 * j]     = sqv[j].x;
            pbuf[wv][128 + j0 + 2 * j + 1] = sqv[j].y;
        }
    }
    __syncthreads();
    int tid = threadIdx.x;
    float s = pbuf[0][tid] + pbuf[1][tid] + pbuf[2][tid] + pbuf[3][tid];
    atomicAdd(&stats[(blockIdx.x & (NREP - 1)) * 256 + tid], s);
}

// ---------------- launch ----------------

static inline char* alignp(char* p, size_t a) {
    return (char*)(((uintptr_t)p + a - 1) & ~(uintptr_t)(a - 1));
}

extern "C" void kernel_launch(void* const* d_in, const int* in_sizes, int n_in,
                              void* d_out, int out_size, void* d_ws, size_t ws_size,
                              hipStream_t stream) {
    const float* x   = (const float*)d_in[0];
    const int*   ei  = (const int*)d_in[1];
    const float* ea  = (const float*)d_in[2];
    const float* Wp[3]  = {(const float*)d_in[3],  (const float*)d_in[9],  (const float*)d_in[15]};
    const float* bp[3]  = {(const float*)d_in[4],  (const float*)d_in[10], (const float*)d_in[16]};
    const float* Wep[3] = {(const float*)d_in[5],  (const float*)d_in[11], (const float*)d_in[17]};
    const float* bep[3] = {(const float*)d_in[6],  (const float*)d_in[12], (const float*)d_in[18]};
    const float* gp[3]  = {(const float*)d_in[7],  (const float*)d_in[13], (const float*)d_in[19]};
    const float* btp[3] = {(const float*)d_in[8],  (const float*)d_in[14], (const float*)d_in[20]};
    const float* Wl  = (const float*)d_in[21];
    const float* bl  = (const float*)d_in[22];
    float* out = (float*)d_out;

    char* p = (char*)d_ws;
    auto alloc = [&](size_t bytes) -> void* {
        p = alignp(p, 256);
        void* r = (void*)p;
        p += bytes;
        return r;
    };

    int*    bcnt     = (int*)alloc(2 * NBUCK * sizeof(int));
    int*    rowCnt   = bcnt;
    int*    colCnt   = bcnt + NBUCK;
    int*    rowBase  = (int*)alloc((NBUCK + 1) * sizeof(int));
    int*    colBase  = (int*)alloc((NBUCK + 1) * sizeof(int));
    int*    rowCur   = (int*)alloc(NBUCK * sizeof(int));
    int*    colCur   = (int*)alloc(NBUCK * sizeof(int));
    int*    offs     = (int*)alloc((NN + 1) * sizeof(int));
    float*  dinv     = (float*)alloc(NN * sizeof(float));
    uchar*  rowScat  = (uchar*)alloc(NE * sizeof(uchar));
    uint4*  csr      = (uint4*)alloc(((size_t)NE + CSR_PAD) * sizeof(uint4));
    ushort* h_bf     = (ushort*)alloc((size_t)NN * DIM * sizeof(ushort));
    ushort* t_bf     = (ushort*)alloc((size_t)NN * DIM * sizeof(ushort));
    ushort* Wt       = (ushort*)alloc(DIM * DIM * sizeof(ushort));
    float*  beff     = (float*)alloc(DIM * sizeof(float));
    float*  sb0      = (float*)alloc((size_t)NREP * 256 * sizeof(float));
    float*  sb1      = (float*)alloc((size_t)NREP * 256 * sizeof(float));

    // tmp (bucket-scattered records) aliases t_bf: both 25.6 MB; tmp dies at
    // k_sort_col, t_bf is first written by layer-1 k_agg (strictly later).
    uint4* tmp = (uint4*)t_bf;

    hipMemsetAsync(bcnt, 0, 2 * NBUCK * sizeof(int), stream);
    hipMemsetAsync(csr + NE, 0, CSR_PAD * sizeof(uint4), stream);  // zero-norm pad
    k_count<<<NB_HIST, 256, 0, stream>>>(ei, rowCnt, colCnt);
    k_scanb<<<1, 512, 0, stream>>>(rowCnt, colCnt, rowBase, colBase, rowCur, colCur);
    k_scat<<<NB_HIST, 256, 0, stream>>>(ei, ea, rowCur, colCur, rowScat, tmp);
    k_deg<<<NBUCK, 1024, 0, stream>>>(rowScat, rowBase, dinv);
    k_sort_col<<<NBUCK, 1024, 0, stream>>>(tmp, colBase, dinv, csr, offs);

    // stats double-buffer: scur(l) = (l&1)? sb1 : sb0; sprev(l) = the other.
    float* sbs[2] = {sb0, sb1};
    for (int l = 0; l < 3; ++l) {
        float* scur = sbs[l & 1];
        float* sprev = sbs[(l + 1) & 1];
        const float* gg = (l == 0) ? gp[0] : gp[l - 1];
        const float* bb = (l == 0) ? btp[0] : btp[l - 1];
        k_prep<<<256, 128, 0, stream>>>(Wp[l], bp[l], gg, bb, sprev, scur,
                                        (l == 0) ? 0 : 1, Wt, beff);
        if (l == 0)
            k_gemm_mf_f32in<<<NBLK_GEMM, 256, 0, stream>>>(x, Wt, beff, h_bf);
        else
            k_gemm_mf_bf<<<NBLK_GEMM, 256, 0, stream>>>(t_bf, Wt, beff, h_bf);
        k_agg<<<NBLK_AGG, 256, 0, stream>>>((const float4*)h_bf, (const float4*)csr, offs,
                                            Wep[l], bep[l], (uint*)t_bf, scur);
    }

    // final linear: BN3 folded (stats in scur(2) = sb0)
    k_prep<<<256, 128, 0, stream>>>(Wl, bl, gp[2], btp[2], sb0, sb1, 1, Wt, beff);
    k_gemm_mf_f32<<<NBLK_GEMM, 256, 0, stream>>>(t_bf, Wt, beff, out);
}

// Round 10
// 679.946 us; speedup vs baseline: 1.1812x; 1.0216x over previous
//
#include <hip/hip_runtime.h>
#include <stdint.h>

#define NN 100000
#define NE 1600000
#define DIM 128
#define BN_EPS 1e-5f
#define NBUCK 391               // ceil(NN/256) col/row buckets of 256 nodes
#define NBLK_GEMM 1563          // ceil(100000/64)
#define NBLK_AGG 6250           // 16 nodes/block: 4 waves x 4 nodes
#define NB_HIST 512             // grid for grid-strided histogram/scatter kernels
#define CSR_PAD 32              // zero-norm pad records past NE (2-deep prefetch)
#define NREP 64                 // stats replica slots (contention: 6250/64 ~= 98 per addr)

typedef unsigned int uint;
typedef unsigned short ushort;
typedef unsigned char uchar;
typedef __attribute__((ext_vector_type(8))) short short8;   // 8 x bf16 (4 VGPRs)
typedef __attribute__((ext_vector_type(4))) float f32x4;
typedef __attribute__((ext_vector_type(2))) float v2f;      // packed fp32 pair

// ---------------- bf16 helpers ----------------

static __device__ __forceinline__ ushort f2bf(float f) {
    uint u = __float_as_uint(f);
    u += 0x7FFF + ((u >> 16) & 1);   // round-to-nearest-even
    return (ushort)(u >> 16);
}
static __device__ __forceinline__ float bf_lo(uint p) { return __uint_as_float(p << 16); }
static __device__ __forceinline__ float bf_hi(uint p) { return __uint_as_float(p & 0xFFFF0000u); }

static __device__ __forceinline__ v2f vfma(v2f a, v2f b, v2f c) {
    return __builtin_elementwise_fma(a, b, c);   // -> v_pk_fma_f32
}
static __device__ __forceinline__ v2f vbc(float s) { v2f r = {s, s}; return r; }

// ============ setup: bucket-sort CSR build ============
// LDS-aggregated histograms (round-8 lesson: device-scope atomics cost ~39B
// fabric-write each at ~27G/s -- LDS hist + per-bucket flush is far cheaper).
// Row and col scatters merged into ONE edge pass (k_scat); norm is filled in
// later by k_sort_col once dinv exists.

__global__ __launch_bounds__(256) void k_count(const int* __restrict__ ei,
                                               int* __restrict__ rowCnt,
                                               int* __restrict__ colCnt) {
    __shared__ int hr[NBUCK], hc[NBUCK];
    int tid = threadIdx.x;
    for (int b = tid; b < NBUCK; b += 256) { hr[b] = 0; hc[b] = 0; }
    __syncthreads();
    const int gstep = NB_HIST * 256;
    const int gt = blockIdx.x * 256 + tid;
    for (int e = gt; e < NE; e += gstep) {
        atomicAdd(&hr[ei[e] >> 8], 1);
        atomicAdd(&hc[ei[NE + e] >> 8], 1);
    }
    __syncthreads();
    for (int b = tid; b < NBUCK; b += 256) {
        if (hr[b]) atomicAdd(&rowCnt[b], hr[b]);
        if (hc[b]) atomicAdd(&colCnt[b], hc[b]);
    }
}

__global__ __launch_bounds__(512) void k_scanb(const int* __restrict__ rowCnt,
                                               const int* __restrict__ colCnt,
                                               int* __restrict__ rowBase,
                                               int* __restrict__ colBase,
                                               int* __restrict__ rowCur,
                                               int* __restrict__ colCur) {
    __shared__ int s[512];
    int tid = threadIdx.x;
    int v = (tid < NBUCK) ? rowCnt[tid] : 0;
    s[tid] = v;
    __syncthreads();
    for (int d = 1; d < 512; d <<= 1) {
        int a = (tid >= d) ? s[tid - d] : 0;
        __syncthreads();
        s[tid] += a;
        __syncthreads();
    }
    if (tid < NBUCK) { int e = s[tid] - v; rowBase[tid] = e; rowCur[tid] = e; }
    if (tid == NBUCK) rowBase[NBUCK] = s[NBUCK];
    __syncthreads();
    v = (tid < NBUCK) ? colCnt[tid] : 0;
    s[tid] = v;
    __syncthreads();
    for (int d = 1; d < 512; d <<= 1) {
        int a = (tid >= d) ? s[tid - d] : 0;
        __syncthreads();
        s[tid] += a;
        __syncthreads();
    }
    if (tid < NBUCK) { int e = s[tid] - v; colBase[tid] = e; colCur[tid] = e; }
    if (tid == NBUCK) colBase[NBUCK] = s[NBUCK];
}

// merged row+col scatter: one edge pass writes rowScat bytes AND col records
// (norm slot left 0 -- filled by k_sort_col after dinv exists).
__global__ __launch_bounds__(256) void k_scat(const int* __restrict__ ei,
                                              const float* __restrict__ ea,
                                              int* __restrict__ rowCur,
                                              int* __restrict__ colCur,
                                              uchar* __restrict__ rowScat,
                                              uint4* __restrict__ tmp) {
    __shared__ int hr[NBUCK], hc[NBUCK], lbr[NBUCK], lbc[NBUCK], lcr[NBUCK], lcc[NBUCK];
    int tid = threadIdx.x;
    for (int b = tid; b < NBUCK; b += 256) { hr[b] = 0; hc[b] = 0; lcr[b] = 0; lcc[b] = 0; }
    __syncthreads();
    const int gstep = NB_HIST * 256;
    const int gt = blockIdx.x * 256 + tid;
    for (int e = gt; e < NE; e += gstep) {
        atomicAdd(&hr[ei[e] >> 8], 1);
        atomicAdd(&hc[ei[NE + e] >> 8], 1);
    }
    __syncthreads();
    for (int b = tid; b < NBUCK; b += 256) {
        lbr[b] = hr[b] ? atomicAdd(&rowCur[b], hr[b]) : 0;
        lbc[b] = hc[b] ? atomicAdd(&colCur[b], hc[b]) : 0;
    }
    __syncthreads();
    for (int e = gt; e < NE; e += gstep) {
        int r = ei[e];
        int c = ei[NE + e];
        int posr = lbr[r >> 8] + atomicAdd(&lcr[r >> 8], 1);
        rowScat[posr] = (uchar)(r & 255);
        float3 eav = *(const float3*)&ea[(size_t)e * 3];   // dwordx3, one inst
        uint4 rec;
        rec.x = 0u;                                   // norm filled in k_sort_col
        rec.y = ((uint)f2bf(eav.x) << 16) | (uint)f2bf(eav.y);
        rec.z = ((uint)f2bf(eav.z) << 16) | (uint)(c & 255);
        rec.w = (uint)r;
        int posc = lbc[c >> 8] + atomicAdd(&lcc[c >> 8], 1);
        tmp[posc] = rec;
    }
}

__global__ __launch_bounds__(1024) void k_deg(const uchar* __restrict__ rowScat,
                                              const int* __restrict__ rowBase,
                                              float* __restrict__ dinv) {
    __shared__ int h[256];
    int tid = threadIdx.x;
    int b = blockIdx.x;
    if (tid < 256) h[tid] = 0;
    __syncthreads();
    int base = rowBase[b], cnt = rowBase[b + 1] - base;
    for (int i = tid; i < cnt; i += 1024) atomicAdd(&h[rowScat[base + i]], 1);
    __syncthreads();
    if (tid < 256) {
        int node = b * 256 + tid;
        if (node < NN) dinv[node] = rsqrtf((float)h[tid] + 1.0f);
    }
}

// per-bucket fine sort -> csr + offs; fills norm = dinv[row]*dinv[col]
__global__ __launch_bounds__(1024) void k_sort_col(const uint4* __restrict__ tmp,
                                                   const int* __restrict__ colBase,
                                                   const float* __restrict__ dinv,
                                                   uint4* __restrict__ csr,
                                                   int* __restrict__ offs) {
    __shared__ int hh[256], sc[256], cur[256];
    __shared__ float dloc[256];
    int tid = threadIdx.x;
    int b = blockIdx.x;
    if (tid < 256) {
        hh[tid] = 0;
        int node = b * 256 + tid;
        dloc[tid] = (node < NN) ? dinv[node] : 0.0f;
    }
    __syncthreads();
    int base = colBase[b], cnt = colBase[b + 1] - base;
    for (int i = tid; i < cnt; i += 1024) atomicAdd(&hh[tmp[base + i].z & 255], 1);
    __syncthreads();
    int v = 0;
    if (tid < 256) { v = hh[tid]; sc[tid] = v; }
    __syncthreads();
    for (int d = 1; d < 256; d <<= 1) {
        int add = 0;
        if (tid < 256 && tid >= d) add = sc[tid - d];
        __syncthreads();
        if (tid < 256) sc[tid] += add;
        __syncthreads();
    }
    if (tid < 256) {
        int excl = sc[tid] - v;
        int node = b * 256 + tid;
        if (node < NN) offs[node] = base + excl;
        if (b == NBUCK - 1 && tid == 0) offs[NN] = NE;
        cur[tid] = excl;
    }
    __syncthreads();
    for (int i = tid; i < cnt; i += 1024) {
        uint4 rec = tmp[base + i];
        int f = rec.z & 255;
        rec.x = __float_as_uint(dinv[(int)rec.w] * dloc[f]);
        int pos = atomicAdd(&cur[f], 1);
        csr[base + pos] = rec;
    }
}

// ---------------- fused BN-fold + weight prep ----------------
// grid 256 x 128. Blocks 0..127: Wt row n (bf16, transposed, A-scaled).
// Blocks 128..255: beff col j. All blocks: zero a 64-elem slice of snext.
// Stats arrive as NREP replica slots; the fold sums replicas (L2-resident).

__global__ __launch_bounds__(128) void k_prep(const float* __restrict__ W,
                                              const float* __restrict__ b,
                                              const float* __restrict__ g,
                                              const float* __restrict__ bt,
                                              const float* __restrict__ sprev,
                                              float* __restrict__ snext,
                                              int mode,
                                              ushort* __restrict__ Wt,
                                              float* __restrict__ beff) {
    __shared__ float s[DIM];
    int k = threadIdx.x;
    // zero next-layer stats replicas: 256 blocks x 64 elems = NREP*256
    if (k < 64) snext[blockIdx.x * 64 + k] = 0.0f;
    float A = 1.0f, B = 0.0f;
    if (mode) {
        float sm = 0.0f, sq = 0.0f;
        for (int r = 0; r < NREP; ++r) {
            sm += sprev[r * 256 + k];
            sq += sprev[r * 256 + 128 + k];
        }
        float m = sm * (1.0f / NN);
        float var = sq * (1.0f / NN) - m * m;
        float rs = rsqrtf(var + BN_EPS);
        A = rs * g[k];
        B = bt[k] - m * A;
    }
    if (blockIdx.x < DIM) {
        int n = blockIdx.x;
        Wt[n * DIM + k] = f2bf(A * W[k * DIM + n]);
    } else {
        int j = blockIdx.x - DIM;
        s[k] = B * W[k * DIM + j];
        __syncthreads();
        for (int d = 64; d > 0; d >>= 1) {
            if (k < d) s[k] += s[k + d];
            __syncthreads();
        }
        if (k == 0) beff[j] = b[j] + s[0];
    }
}

// ---------------- MFMA GEMM: Y[M,128] = A[M,128] @ W + beff ----------------
// OPERAND-SWAPPED: c = mfma(Wt_frag, node_frag) computes D = W^T X^T, so
// D col(lane&15) = node, row(quad*4+reg) = feature [m89 C/D layout]. Each
// lane then holds 4 CONSECUTIVE features of one node -> packed ushort4 /
// float4 stores (8 per lane) instead of 32 scalar 2B stores. Same products,
// same f2bf rounding -> bit-identical output vs the unswapped version.

#define GEMM_LANE_SETUP                                                             \
    const int lane = threadIdx.x & 63;                                              \
    const int wv   = threadIdx.x >> 6;                                              \
    const int m    = lane & 15;                                                     \
    const int quad = lane >> 4;                                                     \
    const int row0 = blockIdx.x * 64 + wv * 16;                                     \
    const int rr   = min(row0 + m, NN - 1);

#define GEMM_MFMA_CORE(a0, a1, a2, a3, Wt)                                          \
    f32x4 acc[8];                                                                   \
    _Pragma("unroll")                                                               \
    for (int ft = 0; ft < 8; ++ft) {                                                \
        const short8* bp = (const short8*)&Wt[(size_t)(ft * 16 + m) * DIM + quad * 8]; \
        f32x4 c = {0.f, 0.f, 0.f, 0.f};                                             \
        c = __builtin_amdgcn_mfma_f32_16x16x32_bf16(bp[0],  a0, c, 0, 0, 0);        \
        c = __builtin_amdgcn_mfma_f32_16x16x32_bf16(bp[4],  a1, c, 0, 0, 0);        \
        c = __builtin_amdgcn_mfma_f32_16x16x32_bf16(bp[8],  a2, c, 0, 0, 0);        \
        c = __builtin_amdgcn_mfma_f32_16x16x32_bf16(bp[12], a3, c, 0, 0, 0);        \
        acc[ft] = c;                                                                \
    }                                                                               \
    const int node = row0 + m;

#define GEMM_STORE_BF16(Y)                                                          \
    if (node < NN) {                                                                \
        ushort* yp = &Y[(size_t)node * DIM + quad * 4];                             \
        _Pragma("unroll")                                                           \
        for (int ft = 0; ft < 8; ++ft) {                                            \
            float4 bb = *(const float4*)&beff[ft * 16 + quad * 4];                  \
            ushort4 o = {f2bf(acc[ft][0] + bb.x), f2bf(acc[ft][1] + bb.y),          \
                         f2bf(acc[ft][2] + bb.z), f2bf(acc[ft][3] + bb.w)};         \
            *(ushort4*)&yp[ft * 16] = o;                                            \
        }                                                                           \
    }

static __device__ __forceinline__ short8 cvt8(float4 a, float4 b) {
    short8 r;
    r[0] = (short)f2bf(a.x); r[1] = (short)f2bf(a.y);
    r[2] = (short)f2bf(a.z); r[3] = (short)f2bf(a.w);
    r[4] = (short)f2bf(b.x); r[5] = (short)f2bf(b.y);
    r[6] = (short)f2bf(b.z); r[7] = (short)f2bf(b.w);
    return r;
}

// layer-1: A is fp32 (input x), converted in-register (same f2bf as x2bf ->
// bit-identical; saves the 51MB x_bf round-trip)
__global__ __launch_bounds__(256) void k_gemm_mf_f32in(const float* __restrict__ Af,
                                                       const ushort* __restrict__ Wt,
                                                       const float* __restrict__ beff,
                                                       ushort* __restrict__ Y) {
    GEMM_LANE_SETUP
    const float4* apf = (const float4*)&Af[(size_t)rr * DIM] + quad * 2;
    short8 a0 = cvt8(apf[0],  apf[1]);
    short8 a1 = cvt8(apf[8],  apf[9]);
    short8 a2 = cvt8(apf[16], apf[17]);
    short8 a3 = cvt8(apf[24], apf[25]);
    GEMM_MFMA_CORE(a0, a1, a2, a3, Wt)
    GEMM_STORE_BF16(Y)
}

__global__ __launch_bounds__(256) void k_gemm_mf_bf(const ushort* __restrict__ Abf,
                                                    const ushort* __restrict__ Wt,
                                                    const float* __restrict__ beff,
                                                    ushort* __restrict__ Y) {
    GEMM_LANE_SETUP
    const short8* ap = (const short8*)&Abf[(size_t)rr * DIM + quad * 8];
    short8 a0 = ap[0];
    short8 a1 = ap[4];
    short8 a2 = ap[8];
    short8 a3 = ap[12];
    GEMM_MFMA_CORE(a0, a1, a2, a3, Wt)
    GEMM_STORE_BF16(Y)
}

__global__ __launch_bounds__(256) void k_gemm_mf_f32(const ushort* __restrict__ Abf,
                                                     const ushort* __restrict__ Wt,
                                                     const float* __restrict__ beff,
                                                     float* __restrict__ Y) {
    GEMM_LANE_SETUP
    const short8* ap = (const short8*)&Abf[(size_t)rr * DIM + quad * 8];
    short8 a0 = ap[0];
    short8 a1 = ap[4];
    short8 a2 = ap[8];
    short8 a3 = ap[12];
    GEMM_MFMA_CORE(a0, a1, a2, a3, Wt)
    if (node < NN) {
        float* yp = &Y[(size_t)node * DIM + quad * 4];
#pragma unroll
        for (int ft = 0; ft < 8; ++ft) {
            float4 bb = *(const float4*)&beff[ft * 16 + quad * 4];
            float4 o = {acc[ft][0] + bb.x, acc[ft][1] + bb.y,
                        acc[ft][2] + bb.z, acc[ft][3] + bb.w};
            *(float4*)&yp[ft * 16] = o;
        }
    }
}

// ---------------- aggregation + fused BN statistics ----------------
// wave processes 4 nodes; 8 edges/iter (lane = q*16 + oc, 4 edge-quads x 2).
// 2-deep software pipeline. BN partials merged per block in LDS, then one
// atomicAdd per thread into a REPLICA slot (blockIdx&63).

static __device__ __forceinline__ void edge_compute(float4 r, float4 hv, float n,
                                                    const v2f* __restrict__ w0,
                                                    const v2f* __restrict__ w1,
                                                    const v2f* __restrict__ w2,
                                                    const v2f* __restrict__ vbe,
                                                    v2f* __restrict__ acc) {
    uint py = __float_as_uint(r.y), pz = __float_as_uint(r.z);
    v2f va0 = vbc(bf_hi(py)), va1 = vbc(bf_lo(py)), va2 = vbc(bf_hi(pz));
    v2f vn = vbc(n);
    uint hx = __float_as_uint(hv.x), hy = __float_as_uint(hv.y);
    uint hz = __float_as_uint(hv.z), hw = __float_as_uint(hv.w);
    v2f hp[4] = {{bf_lo(hx), bf_hi(hx)}, {bf_lo(hy), bf_hi(hy)},
                 {bf_lo(hz), bf_hi(hz)}, {bf_lo(hw), bf_hi(hw)}};
    const v2f z = {0.0f, 0.0f};
#pragma unroll
    for (int j = 0; j < 4; ++j) {
        v2f e = vfma(va2, w2[j], vbe[j]);
        e = vfma(va1, w1[j], e);
        e = vfma(va0, w0[j], e);
        v2f u = hp[j] + e;
        u = __builtin_elementwise_max(u, z);   // v_pk_max_f32
        acc[j] = vfma(vn, u, acc[j]);
    }
}

__global__ __launch_bounds__(256) void k_agg(const float4* __restrict__ h4,
                                             const float4* __restrict__ csr,
                                             const int* __restrict__ offs,
                                             const float* __restrict__ We,
                                             const float* __restrict__ be,
                                             uint* __restrict__ tb,
                                             float* __restrict__ stats) {
    __shared__ float pbuf[4][256];
    int wv = threadIdx.x >> 6;
    int lane = threadIdx.x & 63;
    int q  = lane >> 4;
    int oc = lane & 15;
    int j0 = oc * 8;

    float4 t0, t1;
    t0 = *(const float4*)&We[j0];             t1 = *(const float4*)&We[j0 + 4];
    v2f w0[4] = {{t0.x, t0.y}, {t0.z, t0.w}, {t1.x, t1.y}, {t1.z, t1.w}};
    t0 = *(const float4*)&We[DIM + j0];       t1 = *(const float4*)&We[DIM + j0 + 4];
    v2f w1[4] = {{t0.x, t0.y}, {t0.z, t0.w}, {t1.x, t1.y}, {t1.z, t1.w}};
    t0 = *(const float4*)&We[2 * DIM + j0];   t1 = *(const float4*)&We[2 * DIM + j0 + 4];
    v2f w2[4] = {{t0.x, t0.y}, {t0.z, t0.w}, {t1.x, t1.y}, {t1.z, t1.w}};
    t0 = *(const float4*)&be[j0];             t1 = *(const float4*)&be[j0 + 4];
    v2f vbe[4] = {{t0.x, t0.y}, {t0.z, t0.w}, {t1.x, t1.y}, {t1.z, t1.w}};

    v2f smv[4] = {{0,0},{0,0},{0,0},{0,0}};
    v2f sqv[4] = {{0,0},{0,0},{0,0},{0,0}};

    const int v0 = blockIdx.x * 16 + wv * 4;     // NBLK_AGG*16 == NN exactly
    int ofs[5];
#pragma unroll
    for (int k = 0; k < 5; ++k) ofs[k] = offs[v0 + k];

    for (int it = 0; it < 4; ++it) {
        int v = v0 + it;
        v2f acc[4] = {{0,0},{0,0},{0,0},{0,0}};
        int s0 = ofs[it], e0 = ofs[it + 1];

        // pipeline prologue: issue csr for iter0 AND iter1 together, then
        // h gathers for iter0 (rA wait is the only exposed latency per node)
        float4 rA1 = csr[s0 + q];
        float4 rA2 = csr[s0 + 4 + q];
        float4 rB1 = csr[s0 + 8 + q];
        float4 rB2 = csr[s0 + 12 + q];
        float4 hA1 = h4[(size_t)__float_as_int(rA1.w) * 16 + oc];
        float4 hA2 = h4[(size_t)__float_as_int(rA2.w) * 16 + oc];

#pragma unroll 2
        for (int base = s0; base < e0; base += 8) {
            // stage B: rows -> issue h(B); issue csr(C)
            float4 hB1 = h4[(size_t)__float_as_int(rB1.w) * 16 + oc];
            float4 hB2 = h4[(size_t)__float_as_int(rB2.w) * 16 + oc];
            float4 rC1 = csr[base + 16 + q];
            float4 rC2 = csr[base + 20 + q];
            // stage A compute (hA issued one iteration ago)
            float n1 = (base + q < e0) ? rA1.x : 0.0f;
            float n2 = (base + 4 + q < e0) ? rA2.x : 0.0f;
            edge_compute(rA1, hA1, n1, w0, w1, w2, vbe, acc);
            edge_compute(rA2, hA2, n2, w0, w1, w2, vbe, acc);
            rA1 = rB1; rA2 = rB2; rB1 = rC1; rB2 = rC2;
            hA1 = hB1; hA2 = hB2;
        }

        // reduce across the 4 edge-quads (lanes with equal oc)
#pragma unroll
        for (int j = 0; j < 4; ++j) {
            acc[j].x += __shfl_xor(acc[j].x, 16); acc[j].x += __shfl_xor(acc[j].x, 32);
            acc[j].y += __shfl_xor(acc[j].y, 16); acc[j].y += __shfl_xor(acc[j].y, 32);
        }

        if (q == 0) {
            uint4 pk;
            uint pw[4];
#pragma unroll
            for (int j = 0; j < 4; ++j) {
                acc[j].x = fmaxf(acc[j].x, 0.0f);   // outer relu
                acc[j].y = fmaxf(acc[j].y, 0.0f);
                smv[j] = smv[j] + acc[j];
                sqv[j] = vfma(acc[j], acc[j], sqv[j]);
                pw[j] = ((uint)f2bf(acc[j].y) << 16) | f2bf(acc[j].x);
            }
            pk.x = pw[0]; pk.y = pw[1]; pk.z = pw[2]; pk.w = pw[3];
            *(uint4*)&tb[(size_t)v * 64 + oc * 4] = pk;
        }
    }

    if (q == 0) {
#pragma unroll
        for (int j = 0; j < 4; ++j) {
            pbuf[wv][j0 + 2 * j]       = smv[j].x;
            pbuf[wv][j0 + 2 * j + 1]   = smv[j].y;
            pbuf[wv][128 + j0 + 2 * j]     = sqv[j].x;
            pbuf[wv][128 + j0 + 2 * j + 1] = sqv[j].y;
        }
    }
    __syncthreads();
    int tid = threadIdx.x;
    float s = pbuf[0][tid] + pbuf[1][tid] + pbuf[2][tid] + pbuf[3][tid];
    atomicAdd(&stats[(blockIdx.x & (NREP - 1)) * 256 + tid], s);
}

// ---------------- launch ----------------

static inline char* alignp(char* p, size_t a) {
    return (char*)(((uintptr_t)p + a - 1) & ~(uintptr_t)(a - 1));
}

extern "C" void kernel_launch(void* const* d_in, const int* in_sizes, int n_in,
                              void* d_out, int out_size, void* d_ws, size_t ws_size,
                              hipStream_t stream) {
    const float* x   = (const float*)d_in[0];
    const int*   ei  = (const int*)d_in[1];
    const float* ea  = (const float*)d_in[2];
    const float* Wp[3]  = {(const float*)d_in[3],  (const float*)d_in[9],  (const float*)d_in[15]};
    const float* bp[3]  = {(const float*)d_in[4],  (const float*)d_in[10], (const float*)d_in[16]};
    const float* Wep[3] = {(const float*)d_in[5],  (const float*)d_in[11], (const float*)d_in[17]};
    const float* bep[3] = {(const float*)d_in[6],  (const float*)d_in[12], (const float*)d_in[18]};
    const float* gp[3]  = {(const float*)d_in[7],  (const float*)d_in[13], (const float*)d_in[19]};
    const float* btp[3] = {(const float*)d_in[8],  (const float*)d_in[14], (const float*)d_in[20]};
    const float* Wl  = (const float*)d_in[21];
    const float* bl  = (const float*)d_in[22];
    float* out = (float*)d_out;

    char* p = (char*)d_ws;
    auto alloc = [&](size_t bytes) -> void* {
        p = alignp(p, 256);
        void* r = (void*)p;
        p += bytes;
        return r;
    };

    int*    bcnt     = (int*)alloc(2 * NBUCK * sizeof(int));
    int*    rowCnt   = bcnt;
    int*    colCnt   = bcnt + NBUCK;
    int*    rowBase  = (int*)alloc((NBUCK + 1) * sizeof(int));
    int*    colBase  = (int*)alloc((NBUCK + 1) * sizeof(int));
    int*    rowCur   = (int*)alloc(NBUCK * sizeof(int));
    int*    colCur   = (int*)alloc(NBUCK * sizeof(int));
    int*    offs     = (int*)alloc((NN + 1) * sizeof(int));
    float*  dinv     = (float*)alloc(NN * sizeof(float));
    uchar*  rowScat  = (uchar*)alloc(NE * sizeof(uchar));
    uint4*  csr      = (uint4*)alloc(((size_t)NE + CSR_PAD) * sizeof(uint4));
    ushort* h_bf     = (ushort*)alloc((size_t)NN * DIM * sizeof(ushort));
    ushort* t_bf     = (ushort*)alloc((size_t)NN * DIM * sizeof(ushort));
    ushort* Wt       = (ushort*)alloc(DIM * DIM * sizeof(ushort));
    float*  beff     = (float*)alloc(DIM * sizeof(float));
    float*  sb0      = (float*)alloc((size_t)NREP * 256 * sizeof(float));
    float*  sb1      = (float*)alloc((size_t)NREP * 256 * sizeof(float));

    // tmp (bucket-scattered records) aliases t_bf: both 25.6 MB; tmp dies at
    // k_sort_col, t_bf is first written by layer-1 k_agg (strictly later).
    uint4* tmp = (uint4*)t_bf;

    hipMemsetAsync(bcnt, 0, 2 * NBUCK * sizeof(int), stream);
    hipMemsetAsync(csr + NE, 0, CSR_PAD * sizeof(uint4), stream);  // zero-norm pad
    k_count<<<NB_HIST, 256, 0, stream>>>(ei, rowCnt, colCnt);
    k_scanb<<<1, 512, 0, stream>>>(rowCnt, colCnt, rowBase, colBase, rowCur, colCur);
    k_scat<<<NB_HIST, 256, 0, stream>>>(ei, ea, rowCur, colCur, rowScat, tmp);
    k_deg<<<NBUCK, 1024, 0, stream>>>(rowScat, rowBase, dinv);
    k_sort_col<<<NBUCK, 1024, 0, stream>>>(tmp, colBase, dinv, csr, offs);

    // stats double-buffer: scur(l) = (l&1)? sb1 : sb0; sprev(l) = the other.
    float* sbs[2] = {sb0, sb1};
    for (int l = 0; l < 3; ++l) {
        float* scur = sbs[l & 1];
        float* sprev = sbs[(l + 1) & 1];
        const float* gg = (l == 0) ? gp[0] : gp[l - 1];
        const float* bb = (l == 0) ? btp[0] : btp[l - 1];
        k_prep<<<256, 128, 0, stream>>>(Wp[l], bp[l], gg, bb, sprev, scur,
                                        (l == 0) ? 0 : 1, Wt, beff);
        if (l == 0)
            k_gemm_mf_f32in<<<NBLK_GEMM, 256, 0, stream>>>(x, Wt, beff, h_bf);
        else
            k_gemm_mf_bf<<<NBLK_GEMM, 256, 0, stream>>>(t_bf, Wt, beff, h_bf);
        k_agg<<<NBLK_AGG, 256, 0, stream>>>((const float4*)h_bf, (const float4*)csr, offs,
                                            Wep[l], bep[l], (uint*)t_bf, scur);
    }

    // final linear: BN3 folded (stats in scur(2) = sb0)
    k_prep<<<256, 128, 0, stream>>>(Wl, bl, gp[2], btp[2], sb0, sb1, 1, Wt, beff);
    k_gemm_mf_f32<<<NBLK_GEMM, 256, 0, stream>>>(t_bf, Wt, beff, out);
}

// Round 11
// 623.589 us; speedup vs baseline: 1.2879x; 1.0904x over previous
//
#include <hip/hip_runtime.h>
#include <stdint.h>

#define NN 100000
#define NE 1600000
#define DIM 128
#define BN_EPS 1e-5f
#define NBUCK 391               // ceil(NN/256) col/row buckets of 256 nodes
#define NBLK_GEMM 1563          // ceil(100000/64)
#define NBLK_AGG 6250           // 16 nodes/block: 4 waves x 4 nodes
#define NB_HIST 512             // grid for grid-strided histogram/scatter kernels
#define CSR_PAD 32              // zero-norm pad records past NE (2-deep prefetch)
#define NREP 64                 // stats replica slots
#define WTL_STRIDE 136          // ushorts per row (272 B = 68 dwords -> 2-way banks, free)

typedef unsigned int uint;
typedef unsigned short ushort;
typedef unsigned char uchar;
typedef __attribute__((ext_vector_type(8))) short short8;   // 8 x bf16 (4 VGPRs)
typedef __attribute__((ext_vector_type(4))) float f32x4;
typedef __attribute__((ext_vector_type(2))) float v2f;      // packed fp32 pair

// ---------------- bf16 helpers ----------------

static __device__ __forceinline__ ushort f2bf(float f) {
    uint u = __float_as_uint(f);
    u += 0x7FFF + ((u >> 16) & 1);   // round-to-nearest-even
    return (ushort)(u >> 16);
}
static __device__ __forceinline__ float bf_lo(uint p) { return __uint_as_float(p << 16); }
static __device__ __forceinline__ float bf_hi(uint p) { return __uint_as_float(p & 0xFFFF0000u); }

static __device__ __forceinline__ v2f vfma(v2f a, v2f b, v2f c) {
    return __builtin_elementwise_fma(a, b, c);   // -> v_pk_fma_f32
}
static __device__ __forceinline__ v2f vbc(float s) { v2f r = {s, s}; return r; }

// ============ setup: bucket-sort CSR build ============

__global__ __launch_bounds__(256) void k_count(const int* __restrict__ ei,
                                               int* __restrict__ rowCnt,
                                               int* __restrict__ colCnt) {
    __shared__ int hr[NBUCK], hc[NBUCK];
    int tid = threadIdx.x;
    for (int b = tid; b < NBUCK; b += 256) { hr[b] = 0; hc[b] = 0; }
    __syncthreads();
    const int gstep = NB_HIST * 256;
    const int gt = blockIdx.x * 256 + tid;
    for (int e = gt; e < NE; e += gstep) {
        atomicAdd(&hr[ei[e] >> 8], 1);
        atomicAdd(&hc[ei[NE + e] >> 8], 1);
    }
    __syncthreads();
    for (int b = tid; b < NBUCK; b += 256) {
        if (hr[b]) atomicAdd(&rowCnt[b], hr[b]);
        if (hc[b]) atomicAdd(&colCnt[b], hc[b]);
    }
}

__global__ __launch_bounds__(512) void k_scanb(const int* __restrict__ rowCnt,
                                               const int* __restrict__ colCnt,
                                               int* __restrict__ rowBase,
                                               int* __restrict__ colBase,
                                               int* __restrict__ rowCur,
                                               int* __restrict__ colCur,
                                               uint4* __restrict__ csr) {
    __shared__ int s[512];
    int tid = threadIdx.x;
    // fold the csr-pad zeroing here (pad only read by k_agg, much later)
    if (tid < CSR_PAD * 4) ((uint*)(csr + NE))[tid] = 0u;
    int v = (tid < NBUCK) ? rowCnt[tid] : 0;
    s[tid] = v;
    __syncthreads();
    for (int d = 1; d < 512; d <<= 1) {
        int a = (tid >= d) ? s[tid - d] : 0;
        __syncthreads();
        s[tid] += a;
        __syncthreads();
    }
    if (tid < NBUCK) { int e = s[tid] - v; rowBase[tid] = e; rowCur[tid] = e; }
    if (tid == NBUCK) rowBase[NBUCK] = s[NBUCK];
    __syncthreads();
    v = (tid < NBUCK) ? colCnt[tid] : 0;
    s[tid] = v;
    __syncthreads();
    for (int d = 1; d < 512; d <<= 1) {
        int a = (tid >= d) ? s[tid - d] : 0;
        __syncthreads();
        s[tid] += a;
        __syncthreads();
    }
    if (tid < NBUCK) { int e = s[tid] - v; colBase[tid] = e; colCur[tid] = e; }
    if (tid == NBUCK) colBase[NBUCK] = s[NBUCK];
}

// merged row+col scatter; also writes colFine (fine byte per record) so the
// sort's histogram pass reads 1.6 MB instead of re-reading 25.6 MB of records.
__global__ __launch_bounds__(256) void k_scat(const int* __restrict__ ei,
                                              const float* __restrict__ ea,
                                              int* __restrict__ rowCur,
                                              int* __restrict__ colCur,
                                              uchar* __restrict__ rowScat,
                                              uchar* __restrict__ colFine,
                                              uint4* __restrict__ tmp) {
    __shared__ int hr[NBUCK], hc[NBUCK], lbr[NBUCK], lbc[NBUCK], lcr[NBUCK], lcc[NBUCK];
    int tid = threadIdx.x;
    for (int b = tid; b < NBUCK; b += 256) { hr[b] = 0; hc[b] = 0; lcr[b] = 0; lcc[b] = 0; }
    __syncthreads();
    const int gstep = NB_HIST * 256;
    const int gt = blockIdx.x * 256 + tid;
    for (int e = gt; e < NE; e += gstep) {
        atomicAdd(&hr[ei[e] >> 8], 1);
        atomicAdd(&hc[ei[NE + e] >> 8], 1);
    }
    __syncthreads();
    for (int b = tid; b < NBUCK; b += 256) {
        lbr[b] = hr[b] ? atomicAdd(&rowCur[b], hr[b]) : 0;
        lbc[b] = hc[b] ? atomicAdd(&colCur[b], hc[b]) : 0;
    }
    __syncthreads();
    for (int e = gt; e < NE; e += gstep) {
        int r = ei[e];
        int c = ei[NE + e];
        int posr = lbr[r >> 8] + atomicAdd(&lcr[r >> 8], 1);
        rowScat[posr] = (uchar)(r & 255);
        float3 eav = *(const float3*)&ea[(size_t)e * 3];
        uint4 rec;
        rec.x = 0u;                                   // norm filled in k_sort_col
        rec.y = ((uint)f2bf(eav.x) << 16) | (uint)f2bf(eav.y);
        rec.z = ((uint)f2bf(eav.z) << 16) | (uint)(c & 255);
        rec.w = (uint)r;
        int posc = lbc[c >> 8] + atomicAdd(&lcc[c >> 8], 1);
        tmp[posc] = rec;
        colFine[posc] = (uchar)(c & 255);
    }
}

__global__ __launch_bounds__(1024) void k_deg(const uchar* __restrict__ rowScat,
                                              const int* __restrict__ rowBase,
                                              float* __restrict__ dinv) {
    __shared__ int h[256];
    int tid = threadIdx.x;
    int b = blockIdx.x;
    if (tid < 256) h[tid] = 0;
    __syncthreads();
    int base = rowBase[b], cnt = rowBase[b + 1] - base;
    for (int i = tid; i < cnt; i += 1024) atomicAdd(&h[rowScat[base + i]], 1);
    __syncthreads();
    if (tid < 256) {
        int node = b * 256 + tid;
        if (node < NN) dinv[node] = rsqrtf((float)h[tid] + 1.0f);
    }
}

// per-bucket fine sort -> csr + offs; fills norm = dinv[row]*dinv[col]
__global__ __launch_bounds__(1024) void k_sort_col(const uint4* __restrict__ tmp,
                                                   const uchar* __restrict__ colFine,
                                                   const int* __restrict__ colBase,
                                                   const float* __restrict__ dinv,
                                                   uint4* __restrict__ csr,
                                                   int* __restrict__ offs) {
    __shared__ int hh[256], sc[256], cur[256];
    __shared__ float dloc[256];
    int tid = threadIdx.x;
    int b = blockIdx.x;
    if (tid < 256) {
        hh[tid] = 0;
        int node = b * 256 + tid;
        dloc[tid] = (node < NN) ? dinv[node] : 0.0f;
    }
    __syncthreads();
    int base = colBase[b], cnt = colBase[b + 1] - base;
    for (int i = tid; i < cnt; i += 1024) atomicAdd(&hh[colFine[base + i]], 1);
    __syncthreads();
    int v = 0;
    if (tid < 256) { v = hh[tid]; sc[tid] = v; }
    __syncthreads();
    for (int d = 1; d < 256; d <<= 1) {
        int add = 0;
        if (tid < 256 && tid >= d) add = sc[tid - d];
        __syncthreads();
        if (tid < 256) sc[tid] += add;
        __syncthreads();
    }
    if (tid < 256) {
        int excl = sc[tid] - v;
        int node = b * 256 + tid;
        if (node < NN) offs[node] = base + excl;
        if (b == NBUCK - 1 && tid == 0) offs[NN] = NE;
        cur[tid] = excl;
    }
    __syncthreads();
    for (int i = tid; i < cnt; i += 1024) {
        uint4 rec = tmp[base + i];
        int f = rec.z & 255;
        rec.x = __float_as_uint(dinv[(int)rec.w] * dloc[f]);
        int pos = atomicAdd(&cur[f], 1);
        csr[base + pos] = rec;
    }
}

// ---------------- fused BN-fold + MFMA GEMM ----------------
// k_prep folded in: each block stages A/B from stats replicas, folds W->bf16
// into LDS (stride 272B -> 2-way bank alias only = free), computes beff, and
// blocks 0..255 zero the NEXT stats buffer (written by the later agg dispatch).
// MFMA operand-swapped (r10): lane holds 4 consecutive features of one node
// -> packed ushort4/float4 stores.

#define GEMM_FOLD_PROLOGUE                                                          \
    __shared__ ushort WtL[DIM * WTL_STRIDE];                                        \
    __shared__ float beffL[DIM];                                                    \
    __shared__ float ABs[2 * DIM];                                                  \
    __shared__ float bred[256];                                                     \
    {                                                                               \
        int tid = threadIdx.x;                                                      \
        if (blockIdx.x < 256 && tid < 64) snext[blockIdx.x * 64 + tid] = 0.0f;      \
        if (tid < DIM) {                                                            \
            float A = 1.0f, B = 0.0f;                                               \
            if (mode) {                                                             \
                float sm = 0.0f, sq = 0.0f;                                         \
                for (int r = 0; r < NREP; ++r) {                                    \
                    sm += sprev[r * 256 + tid];                                     \
                    sq += sprev[r * 256 + 128 + tid];                               \
                }                                                                   \
                float mm = sm * (1.0f / NN);                                        \
                float var = sq * (1.0f / NN) - mm * mm;                             \
                float rs = rsqrtf(var + BN_EPS);                                    \
                A = rs * g[tid];                                                    \
                B = bt[tid] - mm * A;                                               \
            }                                                                       \
            ABs[tid] = A; ABs[DIM + tid] = B;                                       \
        }                                                                           \
        __syncthreads();                                                            \
        int n = tid & 127;                                                          \
        int k0 = (tid >> 7) * 64;                                                   \
        float bacc = 0.0f;                                                          \
        for (int kk = 0; kk < 64; kk += 2) {                                        \
            int k = k0 + kk;                                                        \
            float w0v = W[(size_t)k * DIM + n];                                     \
            float w1v = W[(size_t)(k + 1) * DIM + n];                               \
            bacc += ABs[DIM + k] * w0v + ABs[DIM + k + 1] * w1v;                    \
            uint pack = ((uint)f2bf(ABs[k + 1] * w1v) << 16) | (uint)f2bf(ABs[k] * w0v); \
            *(uint*)((char*)WtL + (size_t)n * 272 + (size_t)k * 2) = pack;          \
        }                                                                           \
        bred[tid] = bacc;                                                           \
        __syncthreads();                                                            \
        if (tid < DIM) beffL[tid] = bvec[tid] + bred[tid] + bred[tid + DIM];        \
        __syncthreads();                                                            \
    }

#define GEMM_LANE_SETUP                                                             \
    const int lane = threadIdx.x & 63;                                              \
    const int wv   = threadIdx.x >> 6;                                              \
    const int m    = lane & 15;                                                     \
    const int quad = lane >> 4;                                                     \
    const int row0 = blockIdx.x * 64 + wv * 16;                                     \
    const int rr   = min(row0 + m, NN - 1);

#define GEMM_MFMA_CORE(a0, a1, a2, a3)                                              \
    f32x4 acc[8];                                                                   \
    _Pragma("unroll")                                                               \
    for (int ft = 0; ft < 8; ++ft) {                                                \
        const short8* bp = (const short8*)((const char*)WtL + (size_t)(ft * 16 + m) * 272 + quad * 16); \
        const short8* bq = (const short8*)((const char*)WtL + (size_t)(ft * 16 + m) * 272 + 64 + quad * 16); \
        const short8* br = (const short8*)((const char*)WtL + (size_t)(ft * 16 + m) * 272 + 128 + quad * 16); \
        const short8* bs = (const short8*)((const char*)WtL + (size_t)(ft * 16 + m) * 272 + 192 + quad * 16); \
        f32x4 c = {0.f, 0.f, 0.f, 0.f};                                             \
        c = __builtin_amdgcn_mfma_f32_16x16x32_bf16(bp[0], a0, c, 0, 0, 0);         \
        c = __builtin_amdgcn_mfma_f32_16x16x32_bf16(bq[0], a1, c, 0, 0, 0);         \
        c = __builtin_amdgcn_mfma_f32_16x16x32_bf16(br[0], a2, c, 0, 0, 0);         \
        c = __builtin_amdgcn_mfma_f32_16x16x32_bf16(bs[0], a3, c, 0, 0, 0);         \
        acc[ft] = c;                                                                \
    }                                                                               \
    const int node = row0 + m;

#define GEMM_STORE_BF16(Y)                                                          \
    if (node < NN) {                                                                \
        ushort* yp = &Y[(size_t)node * DIM + quad * 4];                             \
        _Pragma("unroll")                                                           \
        for (int ft = 0; ft < 8; ++ft) {                                            \
            float4 bb = *(const float4*)&beffL[ft * 16 + quad * 4];                 \
            ushort4 o = {f2bf(acc[ft][0] + bb.x), f2bf(acc[ft][1] + bb.y),          \
                         f2bf(acc[ft][2] + bb.z), f2bf(acc[ft][3] + bb.w)};         \
            *(ushort4*)&yp[ft * 16] = o;                                            \
        }                                                                           \
    }

static __device__ __forceinline__ short8 cvt8(float4 a, float4 b) {
    short8 r;
    r[0] = (short)f2bf(a.x); r[1] = (short)f2bf(a.y);
    r[2] = (short)f2bf(a.z); r[3] = (short)f2bf(a.w);
    r[4] = (short)f2bf(b.x); r[5] = (short)f2bf(b.y);
    r[6] = (short)f2bf(b.z); r[7] = (short)f2bf(b.w);
    return r;
}

// layer-1: A is fp32 (input x), converted in-register (bit-identical to x2bf)
__global__ __launch_bounds__(256) void k_gemm_f32in(const float* __restrict__ Af,
                                                    const float* __restrict__ W,
                                                    const float* __restrict__ bvec,
                                                    const float* __restrict__ g,
                                                    const float* __restrict__ bt,
                                                    const float* __restrict__ sprev,
                                                    float* __restrict__ snext,
                                                    int mode,
                                                    ushort* __restrict__ Y) {
    GEMM_FOLD_PROLOGUE
    GEMM_LANE_SETUP
    const float4* apf = (const float4*)&Af[(size_t)rr * DIM] + quad * 2;
    short8 a0 = cvt8(apf[0],  apf[1]);
    short8 a1 = cvt8(apf[8],  apf[9]);
    short8 a2 = cvt8(apf[16], apf[17]);
    short8 a3 = cvt8(apf[24], apf[25]);
    GEMM_MFMA_CORE(a0, a1, a2, a3)
    GEMM_STORE_BF16(Y)
}

__global__ __launch_bounds__(256) void k_gemm_bf(const ushort* __restrict__ Abf,
                                                 const float* __restrict__ W,
                                                 const float* __restrict__ bvec,
                                                 const float* __restrict__ g,
                                                 const float* __restrict__ bt,
                                                 const float* __restrict__ sprev,
                                                 float* __restrict__ snext,
                                                 int mode,
                                                 ushort* __restrict__ Y) {
    GEMM_FOLD_PROLOGUE
    GEMM_LANE_SETUP
    const short8* ap = (const short8*)&Abf[(size_t)rr * DIM + quad * 8];
    short8 a0 = ap[0];
    short8 a1 = ap[4];
    short8 a2 = ap[8];
    short8 a3 = ap[12];
    GEMM_MFMA_CORE(a0, a1, a2, a3)
    GEMM_STORE_BF16(Y)
}

__global__ __launch_bounds__(256) void k_gemm_f32out(const ushort* __restrict__ Abf,
                                                     const float* __restrict__ W,
                                                     const float* __restrict__ bvec,
                                                     const float* __restrict__ g,
                                                     const float* __restrict__ bt,
                                                     const float* __restrict__ sprev,
                                                     float* __restrict__ snext,
                                                     int mode,
                                                     float* __restrict__ Y) {
    GEMM_FOLD_PROLOGUE
    GEMM_LANE_SETUP
    const short8* ap = (const short8*)&Abf[(size_t)rr * DIM + quad * 8];
    short8 a0 = ap[0];
    short8 a1 = ap[4];
    short8 a2 = ap[8];
    short8 a3 = ap[12];
    GEMM_MFMA_CORE(a0, a1, a2, a3)
    if (node < NN) {
        float* yp = &Y[(size_t)node * DIM + quad * 4];
#pragma unroll
        for (int ft = 0; ft < 8; ++ft) {
            float4 bb = *(const float4*)&beffL[ft * 16 + quad * 4];
            float4 o = {acc[ft][0] + bb.x, acc[ft][1] + bb.y,
                        acc[ft][2] + bb.z, acc[ft][3] + bb.w};
            *(float4*)&yp[ft * 16] = o;
        }
    }
}

// ---------------- aggregation + fused BN statistics (UNCHANGED r7 core) ----------------

static __device__ __forceinline__ void edge_compute(float4 r, float4 hv, float n,
                                                    const v2f* __restrict__ w0,
                                                    const v2f* __restrict__ w1,
                                                    const v2f* __restrict__ w2,
                                                    const v2f* __restrict__ vbe,
                                                    v2f* __restrict__ acc) {
    uint py = __float_as_uint(r.y), pz = __float_as_uint(r.z);
    v2f va0 = vbc(bf_hi(py)), va1 = vbc(bf_lo(py)), va2 = vbc(bf_hi(pz));
    v2f vn = vbc(n);
    uint hx = __float_as_uint(hv.x), hy = __float_as_uint(hv.y);
    uint hz = __float_as_uint(hv.z), hw = __float_as_uint(hv.w);
    v2f hp[4] = {{bf_lo(hx), bf_hi(hx)}, {bf_lo(hy), bf_hi(hy)},
                 {bf_lo(hz), bf_hi(hz)}, {bf_lo(hw), bf_hi(hw)}};
    const v2f z = {0.0f, 0.0f};
#pragma unroll
    for (int j = 0; j < 4; ++j) {
        v2f e = vfma(va2, w2[j], vbe[j]);
        e = vfma(va1, w1[j], e);
        e = vfma(va0, w0[j], e);
        v2f u = hp[j] + e;
        u = __builtin_elementwise_max(u, z);   // v_pk_max_f32
        acc[j] = vfma(vn, u, acc[j]);
    }
}

__global__ __launch_bounds__(256) void k_agg(const float4* __restrict__ h4,
                                             const float4* __restrict__ csr,
                                             const int* __restrict__ offs,
                                             const float* __restrict__ We,
                                             const float* __restrict__ be,
                                             uint* __restrict__ tb,
                                             float* __restrict__ stats) {
    __shared__ float pbuf[4][256];
    int wv = threadIdx.x >> 6;
    int lane = threadIdx.x & 63;
    int q  = lane >> 4;
    int oc = lane & 15;
    int j0 = oc * 8;

    float4 t0, t1;
    t0 = *(const float4*)&We[j0];             t1 = *(const float4*)&We[j0 + 4];
    v2f w0[4] = {{t0.x, t0.y}, {t0.z, t0.w}, {t1.x, t1.y}, {t1.z, t1.w}};
    t0 = *(const float4*)&We[DIM + j0];       t1 = *(const float4*)&We[DIM + j0 + 4];
    v2f w1[4] = {{t0.x, t0.y}, {t0.z, t0.w}, {t1.x, t1.y}, {t1.z, t1.w}};
    t0 = *(const float4*)&We[2 * DIM + j0];   t1 = *(const float4*)&We[2 * DIM + j0 + 4];
    v2f w2[4] = {{t0.x, t0.y}, {t0.z, t0.w}, {t1.x, t1.y}, {t1.z, t1.w}};
    t0 = *(const float4*)&be[j0];             t1 = *(const float4*)&be[j0 + 4];
    v2f vbe[4] = {{t0.x, t0.y}, {t0.z, t0.w}, {t1.x, t1.y}, {t1.z, t1.w}};

    v2f smv[4] = {{0,0},{0,0},{0,0},{0,0}};
    v2f sqv[4] = {{0,0},{0,0},{0,0},{0,0}};

    const int v0 = blockIdx.x * 16 + wv * 4;     // NBLK_AGG*16 == NN exactly
    int ofs[5];
#pragma unroll
    for (int k = 0; k < 5; ++k) ofs[k] = offs[v0 + k];

    for (int it = 0; it < 4; ++it) {
        int v = v0 + it;
        v2f acc[4] = {{0,0},{0,0},{0,0},{0,0}};
        int s0 = ofs[it], e0 = ofs[it + 1];

        float4 rA1 = csr[s0 + q];
        float4 rA2 = csr[s0 + 4 + q];
        float4 rB1 = csr[s0 + 8 + q];
        float4 rB2 = csr[s0 + 12 + q];
        float4 hA1 = h4[(size_t)__float_as_int(rA1.w) * 16 + oc];
        float4 hA2 = h4[(size_t)__float_as_int(rA2.w) * 16 + oc];

#pragma unroll 2
        for (int base = s0; base < e0; base += 8) {
            float4 hB1 = h4[(size_t)__float_as_int(rB1.w) * 16 + oc];
            float4 hB2 = h4[(size_t)__float_as_int(rB2.w) * 16 + oc];
            float4 rC1 = csr[base + 16 + q];
            float4 rC2 = csr[base + 20 + q];
            float n1 = (base + q < e0) ? rA1.x : 0.0f;
            float n2 = (base + 4 + q < e0) ? rA2.x : 0.0f;
            edge_compute(rA1, hA1, n1, w0, w1, w2, vbe, acc);
            edge_compute(rA2, hA2, n2, w0, w1, w2, vbe, acc);
            rA1 = rB1; rA2 = rB2; rB1 = rC1; rB2 = rC2;
            hA1 = hB1; hA2 = hB2;
        }

#pragma unroll
        for (int j = 0; j < 4; ++j) {
            acc[j].x += __shfl_xor(acc[j].x, 16); acc[j].x += __shfl_xor(acc[j].x, 32);
            acc[j].y += __shfl_xor(acc[j].y, 16); acc[j].y += __shfl_xor(acc[j].y, 32);
        }

        if (q == 0) {
            uint4 pk;
            uint pw[4];
#pragma unroll
            for (int j = 0; j < 4; ++j) {
                acc[j].x = fmaxf(acc[j].x, 0.0f);   // outer relu
                acc[j].y = fmaxf(acc[j].y, 0.0f);
                smv[j] = smv[j] + acc[j];
                sqv[j] = vfma(acc[j], acc[j], sqv[j]);
                pw[j] = ((uint)f2bf(acc[j].y) << 16) | f2bf(acc[j].x);
            }
            pk.x = pw[0]; pk.y = pw[1]; pk.z = pw[2]; pk.w = pw[3];
            *(uint4*)&tb[(size_t)v * 64 + oc * 4] = pk;
        }
    }

    if (q == 0) {
#pragma unroll
        for (int j = 0; j < 4; ++j) {
            pbuf[wv][j0 + 2 * j]       = smv[j].x;
            pbuf[wv][j0 + 2 * j + 1]   = smv[j].y;
            pbuf[wv][128 + j0 + 2 * j]     = sqv[j].x;
            pbuf[wv][128 + j0 + 2 * j + 1] = sqv[j].y;
        }
    }
    __syncthreads();
    int tid = threadIdx.x;
    float s = pbuf[0][tid] + pbuf[1][tid] + pbuf[2][tid] + pbuf[3][tid];
    atomicAdd(&stats[(blockIdx.x & (NREP - 1)) * 256 + tid], s);
}

// ---------------- launch ----------------

static inline char* alignp(char* p, size_t a) {
    return (char*)(((uintptr_t)p + a - 1) & ~(uintptr_t)(a - 1));
}

extern "C" void kernel_launch(void* const* d_in, const int* in_sizes, int n_in,
                              void* d_out, int out_size, void* d_ws, size_t ws_size,
                              hipStream_t stream) {
    const float* x   = (const float*)d_in[0];
    const int*   ei  = (const int*)d_in[1];
    const float* ea  = (const float*)d_in[2];
    const float* Wp[3]  = {(const float*)d_in[3],  (const float*)d_in[9],  (const float*)d_in[15]};
    const float* bp[3]  = {(const float*)d_in[4],  (const float*)d_in[10], (const float*)d_in[16]};
    const float* Wep[3] = {(const float*)d_in[5],  (const float*)d_in[11], (const float*)d_in[17]};
    const float* bep[3] = {(const float*)d_in[6],  (const float*)d_in[12], (const float*)d_in[18]};
    const float* gp[3]  = {(const float*)d_in[7],  (const float*)d_in[13], (const float*)d_in[19]};
    const float* btp[3] = {(const float*)d_in[8],  (const float*)d_in[14], (const float*)d_in[20]};
    const float* Wl  = (const float*)d_in[21];
    const float* bl  = (const float*)d_in[22];
    float* out = (float*)d_out;

    char* p = (char*)d_ws;
    auto alloc = [&](size_t bytes) -> void* {
        p = alignp(p, 256);
        void* r = (void*)p;
        p += bytes;
        return r;
    };

    int*    bcnt     = (int*)alloc(2 * NBUCK * sizeof(int));
    int*    rowCnt   = bcnt;
    int*    colCnt   = bcnt + NBUCK;
    int*    rowBase  = (int*)alloc((NBUCK + 1) * sizeof(int));
    int*    colBase  = (int*)alloc((NBUCK + 1) * sizeof(int));
    int*    rowCur   = (int*)alloc(NBUCK * sizeof(int));
    int*    colCur   = (int*)alloc(NBUCK * sizeof(int));
    int*    offs     = (int*)alloc((NN + 1) * sizeof(int));
    float*  dinv     = (float*)alloc(NN * sizeof(float));
    uchar*  rowScat  = (uchar*)alloc(NE * sizeof(uchar));
    uchar*  colFine  = (uchar*)alloc(NE * sizeof(uchar));
    uint4*  csr      = (uint4*)alloc(((size_t)NE + CSR_PAD) * sizeof(uint4));
    ushort* h_bf     = (ushort*)alloc((size_t)NN * DIM * sizeof(ushort));
    ushort* t_bf     = (ushort*)alloc((size_t)NN * DIM * sizeof(ushort));
    float*  sb0      = (float*)alloc((size_t)NREP * 256 * sizeof(float));
    float*  sb1      = (float*)alloc((size_t)NREP * 256 * sizeof(float));

    // tmp (bucket-scattered records) aliases t_bf: both 25.6 MB; tmp dies at
    // k_sort_col, t_bf is first written by layer-1 k_agg (strictly later).
    uint4* tmp = (uint4*)t_bf;

    hipMemsetAsync(bcnt, 0, 2 * NBUCK * sizeof(int), stream);
    k_count<<<NB_HIST, 256, 0, stream>>>(ei, rowCnt, colCnt);
    k_scanb<<<1, 512, 0, stream>>>(rowCnt, colCnt, rowBase, colBase, rowCur, colCur, csr);
    k_scat<<<NB_HIST, 256, 0, stream>>>(ei, ea, rowCur, colCur, rowScat, colFine, tmp);
    k_deg<<<NBUCK, 1024, 0, stream>>>(rowScat, rowBase, dinv);
    k_sort_col<<<NBUCK, 1024, 0, stream>>>(tmp, colFine, colBase, dinv, csr, offs);

    // stats ping-pong: stats(l) = sbs[l&1]; gemm(l) reads stats(l-1), zeroes stats(l).
    float* sbs[2] = {sb0, sb1};
    for (int l = 0; l < 3; ++l) {
        float* scur = sbs[l & 1];
        float* sprev = sbs[(l + 1) & 1];
        const float* gg = (l == 0) ? gp[0] : gp[l - 1];
        const float* bb = (l == 0) ? btp[0] : btp[l - 1];
        if (l == 0)
            k_gemm_f32in<<<NBLK_GEMM, 256, 0, stream>>>(x, Wp[0], bp[0], gg, bb,
                                                        sprev, scur, 0, h_bf);
        else
            k_gemm_bf<<<NBLK_GEMM, 256, 0, stream>>>(t_bf, Wp[l], bp[l], gg, bb,
                                                     sprev, scur, 1, h_bf);
        k_agg<<<NBLK_AGG, 256, 0, stream>>>((const float4*)h_bf, (const float4*)csr, offs,
                                            Wep[l], bep[l], (uint*)t_bf, scur);
    }

    // final linear: BN3 folded (stats(2) in sb0; zero target sb1 is dead)
    k_gemm_f32out<<<NBLK_GEMM, 256, 0, stream>>>(t_bf, Wl, bl, gp[2], btp[2],
                                                 sb0, sb1, 1, out);
}